// Round 1
// baseline (1007.492 us; speedup 1.0000x reference)
//
#include <hip/hip_runtime.h>
#include <math.h>

// Problem sizes (fixed by the reference)
#define B_   4
#define T_   1024
#define C_   1024
#define BT_  4096
#define NH_  16
#define HD_  64
#define QB_F 128.0f
#define EPS_F 1e-5f

// scalar workspace slots (floats at d_ws base)
#define SLOT_SUMW_IN   0   // [0]=sum(w_in), [1]=sum|w_in|
#define SLOT_SUMW_OUT  2   // [2]=sum(w_out), [3]=sum|w_out|
#define SLOT_GAMMA_X   4   // max|x| as uint bits
#define SLOT_GAMMA_Y   5   // max|y| as uint bits
#define SLOT_SUMX      8   // [8..11]  per-batch sum(x)
#define SLOT_SUMSQX    12  // [12..15] per-batch sum(x^2)
#define SLOT_SUMY      16
#define SLOT_SUMSQY    20

// ---------------------------------------------------------------- reductions

__global__ void reduce_w_kernel(const float* __restrict__ w, int n4,
                                float* __restrict__ sums)
{
    float s = 0.f, sa = 0.f;
    const int stride = gridDim.x * blockDim.x;
    for (int i = blockIdx.x * blockDim.x + threadIdx.x; i < n4; i += stride) {
        float4 v = ((const float4*)w)[i];
        s  += v.x + v.y + v.z + v.w;
        sa += fabsf(v.x) + fabsf(v.y) + fabsf(v.z) + fabsf(v.w);
    }
    #pragma unroll
    for (int o = 32; o > 0; o >>= 1) {
        s  += __shfl_down(s, o);
        sa += __shfl_down(sa, o);
    }
    __shared__ float sm[8];
    const int lane = threadIdx.x & 63, wid = threadIdx.x >> 6;
    if (lane == 0) { sm[wid] = s; sm[4 + wid] = sa; }
    __syncthreads();
    if (threadIdx.x == 0) {
        atomicAdd(&sums[0], sm[0] + sm[1] + sm[2] + sm[3]);
        atomicAdd(&sums[1], sm[4] + sm[5] + sm[6] + sm[7]);
    }
}

// per-batch sum/sumsq over T*C elements + global max|.|
__global__ void reduce_x_kernel(const float* __restrict__ x, float* __restrict__ scal,
                                int sum_base, int sumsq_base, int gamma_slot)
{
    const int b = blockIdx.y;
    const float4* xb = (const float4*)(x + (size_t)b * T_ * C_);
    const int n4 = T_ * C_ / 4;
    float s = 0.f, ss = 0.f, am = 0.f;
    const int stride = gridDim.x * blockDim.x;
    for (int i = blockIdx.x * blockDim.x + threadIdx.x; i < n4; i += stride) {
        float4 v = xb[i];
        s  += v.x + v.y + v.z + v.w;
        ss += v.x*v.x + v.y*v.y + v.z*v.z + v.w*v.w;
        am = fmaxf(am, fmaxf(fmaxf(fabsf(v.x), fabsf(v.y)),
                             fmaxf(fabsf(v.z), fabsf(v.w))));
    }
    #pragma unroll
    for (int o = 32; o > 0; o >>= 1) {
        s  += __shfl_down(s, o);
        ss += __shfl_down(ss, o);
        am  = fmaxf(am, __shfl_down(am, o));
    }
    __shared__ float sm[12];
    const int lane = threadIdx.x & 63, wid = threadIdx.x >> 6;
    if (lane == 0) { sm[wid] = s; sm[4 + wid] = ss; sm[8 + wid] = am; }
    __syncthreads();
    if (threadIdx.x == 0) {
        atomicAdd(&scal[sum_base + b],   sm[0] + sm[1] + sm[2] + sm[3]);
        atomicAdd(&scal[sumsq_base + b], sm[4] + sm[5] + sm[6] + sm[7]);
        float m = fmaxf(fmaxf(sm[8], sm[9]), fmaxf(sm[10], sm[11]));
        atomicMax((unsigned int*)&scal[gamma_slot], __float_as_uint(m));
    }
}

// ---------------------------------------------------------------- bit-GEMM
// Out[row, o] = out_scale * sum_i clip((A[row,i]-mu_b)*am, lo, hi) * sign(W[o,i]-alpha)
// A: [4096 x 1024] row-major, W: [N x 1024] row-major, Out: [4096 x N]
#define GBM 128
#define GBN 128
#define GBK 32

__global__ __launch_bounds__(256) void bit_gemm_kernel(
    const float* __restrict__ A, const float* __restrict__ W,
    float* __restrict__ Out, const float* __restrict__ scal,
    int N, int sumw_slot, int gamma_slot, int sum_base, int sumsq_base,
    float inv_nw)
{
    __shared__ float As[GBK][GBM + 4];
    __shared__ float Ws[GBK][GBN + 4];

    const int tid  = threadIdx.x;
    const int row0 = blockIdx.y * GBM;
    const int col0 = blockIdx.x * GBN;
    const int b    = row0 / T_;           // GBM divides T_, so one batch per block

    const float alpha = scal[sumw_slot]     * inv_nw;
    const float beta  = scal[sumw_slot + 1] * inv_nw;
    const float gamma = __uint_as_float(((const unsigned int*)scal)[gamma_slot]);
    const float invTC = 1.0f / (float)(T_ * C_);
    const float mu    = scal[sum_base + b] * invTC;
    const float var   = scal[sumsq_base + b] * invTC - mu * mu;
    const float isg   = 1.0f / sqrtf(var + EPS_F);
    const float am    = isg * (QB_F / gamma);
    const float qlo   = -QB_F + EPS_F, qhi = QB_F - EPS_F;
    const float out_scale = beta * gamma / QB_F;

    const int ty = tid >> 4;   // 0..15
    const int tx = tid & 15;

    float acc[8][8];
    #pragma unroll
    for (int i = 0; i < 8; ++i)
        #pragma unroll
        for (int j = 0; j < 8; ++j) acc[i][j] = 0.f;

    for (int kt = 0; kt < C_ / GBK; ++kt) {
        __syncthreads();
        #pragma unroll
        for (int it = 0; it < 4; ++it) {
            int slot = it * 256 + tid;          // 0..1023
            int r  = slot >> 3;                 // 0..127
            int k0 = (slot & 7) << 2;           // 0,4,..,28
            float4 av = *(const float4*)&A[(size_t)(row0 + r) * C_ + kt * GBK + k0];
            float4 wv = *(const float4*)&W[(size_t)(col0 + r) * C_ + kt * GBK + k0];
            As[k0+0][r] = fminf(fmaxf((av.x - mu) * am, qlo), qhi);
            As[k0+1][r] = fminf(fmaxf((av.y - mu) * am, qlo), qhi);
            As[k0+2][r] = fminf(fmaxf((av.z - mu) * am, qlo), qhi);
            As[k0+3][r] = fminf(fmaxf((av.w - mu) * am, qlo), qhi);
            Ws[k0+0][r] = (wv.x > alpha) ? 1.0f : ((wv.x < alpha) ? -1.0f : 0.0f);
            Ws[k0+1][r] = (wv.y > alpha) ? 1.0f : ((wv.y < alpha) ? -1.0f : 0.0f);
            Ws[k0+2][r] = (wv.z > alpha) ? 1.0f : ((wv.z < alpha) ? -1.0f : 0.0f);
            Ws[k0+3][r] = (wv.w > alpha) ? 1.0f : ((wv.w < alpha) ? -1.0f : 0.0f);
        }
        __syncthreads();
        #pragma unroll 8
        for (int k = 0; k < GBK; ++k) {
            float af[8], bf[8];
            *(float4*)&af[0] = *(const float4*)&As[k][ty * 4];
            *(float4*)&af[4] = *(const float4*)&As[k][64 + ty * 4];
            *(float4*)&bf[0] = *(const float4*)&Ws[k][tx * 4];
            *(float4*)&bf[4] = *(const float4*)&Ws[k][64 + tx * 4];
            #pragma unroll
            for (int i = 0; i < 8; ++i)
                #pragma unroll
                for (int j = 0; j < 8; ++j)
                    acc[i][j] += af[i] * bf[j];
        }
    }

    #pragma unroll
    for (int i = 0; i < 8; ++i) {
        int gr = row0 + ((i < 4) ? (ty * 4 + i) : (64 + ty * 4 + (i - 4)));
        float4 o0, o1;
        o0.x = acc[i][0] * out_scale; o0.y = acc[i][1] * out_scale;
        o0.z = acc[i][2] * out_scale; o0.w = acc[i][3] * out_scale;
        o1.x = acc[i][4] * out_scale; o1.y = acc[i][5] * out_scale;
        o1.z = acc[i][6] * out_scale; o1.w = acc[i][7] * out_scale;
        *(float4*)&Out[(size_t)gr * N + col0 + tx * 4]      = o0;
        *(float4*)&Out[(size_t)gr * N + col0 + 64 + tx * 4] = o1;
    }
}

// ---------------------------------------------------------------- attention
// One block per (qt, h, b): 64 q-rows, flash-style over k-tiles of 64.
// S and softmax live in registers; P redistributed across lanes via __shfl.
__global__ __launch_bounds__(256) void attention_kernel(
    const float* __restrict__ qkv, float* __restrict__ y)
{
    __shared__ float Qt[HD_][64];   // [d][r]
    __shared__ float Kt[HD_][64];   // [d][c]
    __shared__ float Vs[64][HD_];   // [c][d]

    const int tid = threadIdx.x;
    const int qt = blockIdx.x, h = blockIdx.y, b = blockIdx.z;
    const int q0 = qt * 64;
    const size_t rs = 3 * C_;
    const size_t baseBH = (size_t)b * T_ * rs + (size_t)h * HD_;
    const int ti = tid >> 4, tj = tid & 15;

    #pragma unroll
    for (int it = 0; it < 4; ++it) {
        int slot = it * 256 + tid;
        int r = slot >> 4, d0 = (slot & 15) * 4;
        float4 v = *(const float4*)&qkv[baseBH + (size_t)(q0 + r) * rs + d0];
        Qt[d0+0][r] = v.x; Qt[d0+1][r] = v.y; Qt[d0+2][r] = v.z; Qt[d0+3][r] = v.w;
    }

    float O[4][4];
    float m_run[4], l_run[4];
    #pragma unroll
    for (int i = 0; i < 4; ++i) {
        m_run[i] = -1e30f; l_run[i] = 0.f;
        #pragma unroll
        for (int j = 0; j < 4; ++j) O[i][j] = 0.f;
    }

    for (int kt = 0; kt <= qt; ++kt) {
        __syncthreads();   // previous PV done before overwriting Kt/Vs
        #pragma unroll
        for (int it = 0; it < 4; ++it) {
            int slot = it * 256 + tid;
            int r = slot >> 4, d0 = (slot & 15) * 4;
            float4 kv = *(const float4*)&qkv[baseBH + C_     + (size_t)(kt*64 + r) * rs + d0];
            float4 vv = *(const float4*)&qkv[baseBH + 2*C_   + (size_t)(kt*64 + r) * rs + d0];
            Kt[d0+0][r] = kv.x; Kt[d0+1][r] = kv.y; Kt[d0+2][r] = kv.z; Kt[d0+3][r] = kv.w;
            *(float4*)&Vs[r][d0] = vv;
        }
        __syncthreads();

        float s[4][4];
        #pragma unroll
        for (int i = 0; i < 4; ++i)
            #pragma unroll
            for (int j = 0; j < 4; ++j) s[i][j] = 0.f;

        #pragma unroll 8
        for (int d = 0; d < HD_; ++d) {
            float qa[4], ka[4];
            *(float4*)qa = *(const float4*)&Qt[d][ti * 4];
            *(float4*)ka = *(const float4*)&Kt[d][tj * 4];
            #pragma unroll
            for (int i = 0; i < 4; ++i)
                #pragma unroll
                for (int j = 0; j < 4; ++j)
                    s[i][j] += qa[i] * ka[j];
        }

        #pragma unroll
        for (int i = 0; i < 4; ++i) {
            int qrow = q0 + ti * 4 + i;
            #pragma unroll
            for (int j = 0; j < 4; ++j) {
                int kcol = kt * 64 + tj * 4 + j;
                s[i][j] = (kcol <= qrow) ? s[i][j] * 0.125f : -1e30f;
            }
        }

        float p[4][4], scale_i[4];
        #pragma unroll
        for (int i = 0; i < 4; ++i) {
            float tm = fmaxf(fmaxf(s[i][0], s[i][1]), fmaxf(s[i][2], s[i][3]));
            tm = fmaxf(tm, __shfl_xor(tm, 1));
            tm = fmaxf(tm, __shfl_xor(tm, 2));
            tm = fmaxf(tm, __shfl_xor(tm, 4));
            tm = fmaxf(tm, __shfl_xor(tm, 8));
            float mnew = fmaxf(m_run[i], tm);
            scale_i[i] = __expf(m_run[i] - mnew);
            float ts = 0.f;
            #pragma unroll
            for (int j = 0; j < 4; ++j) { p[i][j] = __expf(s[i][j] - mnew); ts += p[i][j]; }
            ts += __shfl_xor(ts, 1); ts += __shfl_xor(ts, 2);
            ts += __shfl_xor(ts, 4); ts += __shfl_xor(ts, 8);
            l_run[i] = l_run[i] * scale_i[i] + ts;
            m_run[i] = mnew;
        }
        #pragma unroll
        for (int i = 0; i < 4; ++i)
            #pragma unroll
            for (int j = 0; j < 4; ++j) O[i][j] *= scale_i[i];

        const int baseLane = tid & 48;   // (ti%4)*16 within the wave
        #pragma unroll 4
        for (int c4 = 0; c4 < 16; ++c4) {
            int src = baseLane + c4;
            #pragma unroll
            for (int jj = 0; jj < 4; ++jj) {
                float4 vf = *(const float4*)&Vs[c4 * 4 + jj][tj * 4];
                float p0 = __shfl(p[0][jj], src);
                float p1 = __shfl(p[1][jj], src);
                float p2 = __shfl(p[2][jj], src);
                float p3 = __shfl(p[3][jj], src);
                O[0][0] += p0 * vf.x; O[0][1] += p0 * vf.y; O[0][2] += p0 * vf.z; O[0][3] += p0 * vf.w;
                O[1][0] += p1 * vf.x; O[1][1] += p1 * vf.y; O[1][2] += p1 * vf.z; O[1][3] += p1 * vf.w;
                O[2][0] += p2 * vf.x; O[2][1] += p2 * vf.y; O[2][2] += p2 * vf.z; O[2][3] += p2 * vf.w;
                O[3][0] += p3 * vf.x; O[3][1] += p3 * vf.y; O[3][2] += p3 * vf.z; O[3][3] += p3 * vf.w;
            }
        }
    }

    #pragma unroll
    for (int i = 0; i < 4; ++i) {
        float inv = 1.0f / l_run[i];
        float4 o;
        o.x = O[i][0] * inv; o.y = O[i][1] * inv;
        o.z = O[i][2] * inv; o.w = O[i][3] * inv;
        *(float4*)&y[(size_t)(b * T_ + q0 + ti * 4 + i) * C_ + h * HD_ + tj * 4] = o;
    }
}

// ---------------------------------------------------------------- launch

extern "C" void kernel_launch(void* const* d_in, const int* in_sizes, int n_in,
                              void* d_out, int out_size, void* d_ws, size_t ws_size,
                              hipStream_t stream)
{
    (void)in_sizes; (void)n_in; (void)out_size; (void)ws_size;
    const float* x     = (const float*)d_in[0];
    const float* w_in  = (const float*)d_in[1];
    const float* w_out = (const float*)d_in[2];
    float* out  = (float*)d_out;
    float* scal = (float*)d_ws;
    float* qkv  = scal + 64;                       // +256 B
    float* y    = qkv + (size_t)BT_ * (3 * C_);    // +48 MB

    hipMemsetAsync(d_ws, 0, 256, stream);

    reduce_w_kernel<<<dim3(256), 256, 0, stream>>>(w_in,  3 * C_ * C_ / 4, &scal[SLOT_SUMW_IN]);
    reduce_w_kernel<<<dim3(128), 256, 0, stream>>>(w_out, C_ * C_ / 4,     &scal[SLOT_SUMW_OUT]);
    reduce_x_kernel<<<dim3(128, B_), 256, 0, stream>>>(x, scal, SLOT_SUMX, SLOT_SUMSQX, SLOT_GAMMA_X);

    bit_gemm_kernel<<<dim3(3 * C_ / GBN, BT_ / GBM), 256, 0, stream>>>(
        x, w_in, qkv, scal, 3 * C_, SLOT_SUMW_IN, SLOT_GAMMA_X, SLOT_SUMX, SLOT_SUMSQX,
        1.0f / (float)(3 * C_ * C_));

    attention_kernel<<<dim3(T_ / 64, NH_, B_), 256, 0, stream>>>(qkv, y);

    reduce_x_kernel<<<dim3(128, B_), 256, 0, stream>>>(y, scal, SLOT_SUMY, SLOT_SUMSQY, SLOT_GAMMA_Y);

    bit_gemm_kernel<<<dim3(C_ / GBN, BT_ / GBM), 256, 0, stream>>>(
        y, w_out, out, scal, C_, SLOT_SUMW_OUT, SLOT_GAMMA_Y, SLOT_SUMY, SLOT_SUMSQY,
        1.0f / (float)(C_ * C_));
}

// Round 5
// 620.645 us; speedup vs baseline: 1.6233x; 1.6233x over previous
//
#include <hip/hip_runtime.h>
#include <math.h>

// Problem sizes (fixed by the reference)
#define B_   4
#define T_   1024
#define C_   1024
#define BT_  4096
#define NH_  16
#define HD_  64
#define QB_F 128.0f
#define EPS_F 1e-5f
#define KTOT 2048   // hi|lo concatenated K

// scalar workspace slots (floats at d_ws base)
#define SLOT_SUMW_IN   0
#define SLOT_SUMW_OUT  2
#define SLOT_GAMMA_X   4
#define SLOT_GAMMA_Y   5
#define SLOT_SUMX      8
#define SLOT_SUMSQX    12
#define SLOT_SUMY      16
#define SLOT_SUMSQY    20

typedef __attribute__((ext_vector_type(8))) _Float16 half8;
typedef __attribute__((ext_vector_type(4))) _Float16 half4;
typedef __attribute__((ext_vector_type(4))) float    f32x4;

// ---------------------------------------------------------------- reductions

__global__ void reduce_w_kernel(const float* __restrict__ w, int n4,
                                float* __restrict__ sums)
{
    float s = 0.f, sa = 0.f;
    const int stride = gridDim.x * blockDim.x;
    for (int i = blockIdx.x * blockDim.x + threadIdx.x; i < n4; i += stride) {
        float4 v = ((const float4*)w)[i];
        s  += v.x + v.y + v.z + v.w;
        sa += fabsf(v.x) + fabsf(v.y) + fabsf(v.z) + fabsf(v.w);
    }
    #pragma unroll
    for (int o = 32; o > 0; o >>= 1) {
        s  += __shfl_down(s, o);
        sa += __shfl_down(sa, o);
    }
    __shared__ float sm[8];
    const int lane = threadIdx.x & 63, wid = threadIdx.x >> 6;
    if (lane == 0) { sm[wid] = s; sm[4 + wid] = sa; }
    __syncthreads();
    if (threadIdx.x == 0) {
        atomicAdd(&sums[0], sm[0] + sm[1] + sm[2] + sm[3]);
        atomicAdd(&sums[1], sm[4] + sm[5] + sm[6] + sm[7]);
    }
}

__global__ void reduce_x_kernel(const float* __restrict__ x, float* __restrict__ scal,
                                int sum_base, int sumsq_base, int gamma_slot)
{
    const int b = blockIdx.y;
    const float4* xb = (const float4*)(x + (size_t)b * T_ * C_);
    const int n4 = T_ * C_ / 4;
    float s = 0.f, ss = 0.f, am = 0.f;
    const int stride = gridDim.x * blockDim.x;
    for (int i = blockIdx.x * blockDim.x + threadIdx.x; i < n4; i += stride) {
        float4 v = xb[i];
        s  += v.x + v.y + v.z + v.w;
        ss += v.x*v.x + v.y*v.y + v.z*v.z + v.w*v.w;
        am = fmaxf(am, fmaxf(fmaxf(fabsf(v.x), fabsf(v.y)),
                             fmaxf(fabsf(v.z), fabsf(v.w))));
    }
    #pragma unroll
    for (int o = 32; o > 0; o >>= 1) {
        s  += __shfl_down(s, o);
        ss += __shfl_down(ss, o);
        am  = fmaxf(am, __shfl_down(am, o));
    }
    __shared__ float sm[12];
    const int lane = threadIdx.x & 63, wid = threadIdx.x >> 6;
    if (lane == 0) { sm[wid] = s; sm[4 + wid] = ss; sm[8 + wid] = am; }
    __syncthreads();
    if (threadIdx.x == 0) {
        atomicAdd(&scal[sum_base + b],   sm[0] + sm[1] + sm[2] + sm[3]);
        atomicAdd(&scal[sumsq_base + b], sm[4] + sm[5] + sm[6] + sm[7]);
        float m = fmaxf(fmaxf(sm[8], sm[9]), fmaxf(sm[10], sm[11]));
        atomicMax((unsigned int*)&scal[gamma_slot], __float_as_uint(m));
    }
}

// ---------------------------------------------------------------- quantize passes
// act: src [4096][1024] f32 -> dst [4096][2048] fp16, cols 0..1023 = hi(quant),
// cols 1024..2047 = lo residual (hi+lo == quant to ~2^-22 rel).
__global__ void quant_act_kernel(const float* __restrict__ src, unsigned short* __restrict__ dst,
                                 const float* __restrict__ scal,
                                 int sum_base, int sumsq_base, int gamma_slot)
{
    const int n4 = BT_ * C_ / 4;
    const int stride = gridDim.x * blockDim.x;
    const float gamma = scal[gamma_slot];
    const float invTC = 1.0f / (float)(T_ * C_);
    const float qlo = -QB_F + EPS_F, qhi = QB_F - EPS_F;
    for (int i = blockIdx.x * blockDim.x + threadIdx.x; i < n4; i += stride) {
        const int row = i >> 8;            // 256 float4-chunks per row
        const int k   = (i & 255) * 4;
        const int b   = row >> 10;
        const float mu  = scal[sum_base + b] * invTC;
        const float var = scal[sumsq_base + b] * invTC - mu * mu;
        const float am  = (QB_F / gamma) / sqrtf(var + EPS_F);
        float4 v = ((const float4*)src)[i];
        float q[4];
        q[0] = fminf(fmaxf((v.x - mu) * am, qlo), qhi);
        q[1] = fminf(fmaxf((v.y - mu) * am, qlo), qhi);
        q[2] = fminf(fmaxf((v.z - mu) * am, qlo), qhi);
        q[3] = fminf(fmaxf((v.w - mu) * am, qlo), qhi);
        half4 hi, lo;
        #pragma unroll
        for (int j = 0; j < 4; ++j) {
            _Float16 h = (_Float16)q[j];
            hi[j] = h;
            lo[j] = (_Float16)(q[j] - (float)h);
        }
        *(half4*)&dst[(size_t)row * KTOT + k]        = hi;
        *(half4*)&dst[(size_t)row * KTOT + 1024 + k] = lo;
    }
}

// w: src [N][1024] f32 -> dst [N][2048] fp16 sign(w - alpha), duplicated in both K-halves
__global__ void quant_w_kernel(const float* __restrict__ w, unsigned short* __restrict__ dst,
                               const float* __restrict__ scal, int sumw_slot, float inv_nw,
                               int n4)
{
    const float alpha = scal[sumw_slot] * inv_nw;
    const int stride = gridDim.x * blockDim.x;
    for (int i = blockIdx.x * blockDim.x + threadIdx.x; i < n4; i += stride) {
        const int row = i >> 8;
        const int k   = (i & 255) * 4;
        float4 v = ((const float4*)w)[i];
        half4 s;
        s[0] = (v.x > alpha) ? (_Float16)1.0f : ((v.x < alpha) ? (_Float16)-1.0f : (_Float16)0.0f);
        s[1] = (v.y > alpha) ? (_Float16)1.0f : ((v.y < alpha) ? (_Float16)-1.0f : (_Float16)0.0f);
        s[2] = (v.z > alpha) ? (_Float16)1.0f : ((v.z < alpha) ? (_Float16)-1.0f : (_Float16)0.0f);
        s[3] = (v.w > alpha) ? (_Float16)1.0f : ((v.w < alpha) ? (_Float16)-1.0f : (_Float16)0.0f);
        *(half4*)&dst[(size_t)row * KTOT + k]        = s;
        *(half4*)&dst[(size_t)row * KTOT + 1024 + k] = s;
    }
}

// ---------------------------------------------------------------- MFMA GEMM
// C[r][o] = out_scale * sum_k A[r][k] * Wq[o][k]; A [M][2048] fp16, Wq [N][2048] fp16.
// m97 structure: 128x128 tile, BK=32, 4 waves (2x2), 16x16x32 MFMA, global_load_lds w16.

__device__ __forceinline__ void gload_lds16(const void* g, void* l)
{
    __builtin_amdgcn_global_load_lds(
        (const __attribute__((address_space(1))) unsigned int*)g,
        (__attribute__((address_space(3))) unsigned int*)l, 16, 0, 0);
}

__global__ __launch_bounds__(256) void mfma_gemm_kernel(
    const unsigned short* __restrict__ A,   // [M][2048]
    const unsigned short* __restrict__ Bm,  // [N][2048]
    float* __restrict__ Out,                // [M][N]
    const float* __restrict__ scal, int N,
    int sumw_slot, int gamma_slot, float inv_nw)
{
    __shared__ __attribute__((aligned(16))) unsigned short As[128 * 32];
    __shared__ __attribute__((aligned(16))) unsigned short Bs[128 * 32];

    const int tid  = threadIdx.x;
    const int row0 = blockIdx.y * 128;
    const int col0 = blockIdx.x * 128;

    const float beta  = scal[sumw_slot + 1] * inv_nw;
    const float gamma = scal[gamma_slot];
    const float out_scale = beta * gamma / QB_F;

    const int wid = tid >> 6, lane = tid & 63;
    const int wr = (wid >> 1) * 64, wc = (wid & 1) * 64;
    const int lrow = lane & 15, lk = (lane >> 4) * 8;

    // staging chunk: lds bytes = wave_base + lane*16 (linear), c = tid -> row=c>>2, col8=(c&3)*8
    const int c0r = tid >> 2;
    const int c0k = (tid & 3) * 8;

    f32x4 acc[4][4];
    #pragma unroll
    for (int m = 0; m < 4; ++m)
        #pragma unroll
        for (int n = 0; n < 4; ++n)
            acc[m][n] = (f32x4){0.f, 0.f, 0.f, 0.f};

    for (int kt = 0; kt < KTOT; kt += 32) {
        __syncthreads();
        gload_lds16(&A [(size_t)(row0 +      c0r) * KTOT + kt + c0k], &As[c0r * 32 + c0k]);
        gload_lds16(&A [(size_t)(row0 + 64 + c0r) * KTOT + kt + c0k], &As[(64 + c0r) * 32 + c0k]);
        gload_lds16(&Bm[(size_t)(col0 +      c0r) * KTOT + kt + c0k], &Bs[c0r * 32 + c0k]);
        gload_lds16(&Bm[(size_t)(col0 + 64 + c0r) * KTOT + kt + c0k], &Bs[(64 + c0r) * 32 + c0k]);
        __syncthreads();

        half8 a[4], b[4];
        #pragma unroll
        for (int m = 0; m < 4; ++m)
            a[m] = *(const half8*)&As[(wr + m * 16 + lrow) * 32 + lk];
        #pragma unroll
        for (int n = 0; n < 4; ++n)
            b[n] = *(const half8*)&Bs[(wc + n * 16 + lrow) * 32 + lk];
        #pragma unroll
        for (int m = 0; m < 4; ++m)
            #pragma unroll
            for (int n = 0; n < 4; ++n)
                acc[m][n] = __builtin_amdgcn_mfma_f32_16x16x32_f16(a[m], b[n], acc[m][n], 0, 0, 0);
    }

    // epilogue: D layout col = lane&15, row = (lane>>4)*4 + q  [guide §3, m89-verified]
    const int orow = (lane >> 4) * 4;
    const int ocol = lane & 15;
    #pragma unroll
    for (int m = 0; m < 4; ++m)
        #pragma unroll
        for (int n = 0; n < 4; ++n)
            #pragma unroll
            for (int q = 0; q < 4; ++q)
                Out[(size_t)(row0 + wr + m * 16 + orow + q) * N + col0 + wc + n * 16 + ocol]
                    = acc[m][n][q] * out_scale;
}

// ---------------------------------------------------------------- attention
// Heavy-first LPT ordering: qt = gridDim.x-1-blockIdx.x so the long diagonal
// blocks (work ∝ qt+1) dispatch first — pure permutation, bit-identical output.
__global__ __launch_bounds__(256) void attention_kernel(
    const float* __restrict__ qkv, float* __restrict__ y)
{
    __shared__ float Qt[HD_][64];
    __shared__ float Kt[HD_][64];
    __shared__ float Vs[64][HD_];

    const int tid = threadIdx.x;
    const int qt = gridDim.x - 1 - blockIdx.x;   // LPT: heavy blocks first
    const int h = blockIdx.y, b = blockIdx.z;
    const int q0 = qt * 64;
    const size_t rs = 3 * C_;
    const size_t baseBH = (size_t)b * T_ * rs + (size_t)h * HD_;
    const int ti = tid >> 4, tj = tid & 15;

    #pragma unroll
    for (int it = 0; it < 4; ++it) {
        int slot = it * 256 + tid;
        int r = slot >> 4, d0 = (slot & 15) * 4;
        float4 v = *(const float4*)&qkv[baseBH + (size_t)(q0 + r) * rs + d0];
        Qt[d0+0][r] = v.x; Qt[d0+1][r] = v.y; Qt[d0+2][r] = v.z; Qt[d0+3][r] = v.w;
    }

    float O[4][4];
    float m_run[4], l_run[4];
    #pragma unroll
    for (int i = 0; i < 4; ++i) {
        m_run[i] = -1e30f; l_run[i] = 0.f;
        #pragma unroll
        for (int j = 0; j < 4; ++j) O[i][j] = 0.f;
    }

    for (int kt = 0; kt <= qt; ++kt) {
        __syncthreads();
        #pragma unroll
        for (int it = 0; it < 4; ++it) {
            int slot = it * 256 + tid;
            int r = slot >> 4, d0 = (slot & 15) * 4;
            float4 kv = *(const float4*)&qkv[baseBH + C_   + (size_t)(kt*64 + r) * rs + d0];
            float4 vv = *(const float4*)&qkv[baseBH + 2*C_ + (size_t)(kt*64 + r) * rs + d0];
            Kt[d0+0][r] = kv.x; Kt[d0+1][r] = kv.y; Kt[d0+2][r] = kv.z; Kt[d0+3][r] = kv.w;
            *(float4*)&Vs[r][d0] = vv;
        }
        __syncthreads();

        float s[4][4];
        #pragma unroll
        for (int i = 0; i < 4; ++i)
            #pragma unroll
            for (int j = 0; j < 4; ++j) s[i][j] = 0.f;

        #pragma unroll 8
        for (int d = 0; d < HD_; ++d) {
            float qa[4], ka[4];
            *(float4*)qa = *(const float4*)&Qt[d][ti * 4];
            *(float4*)ka = *(const float4*)&Kt[d][tj * 4];
            #pragma unroll
            for (int i = 0; i < 4; ++i)
                #pragma unroll
                for (int j = 0; j < 4; ++j)
                    s[i][j] += qa[i] * ka[j];
        }

        #pragma unroll
        for (int i = 0; i < 4; ++i) {
            int qrow = q0 + ti * 4 + i;
            #pragma unroll
            for (int j = 0; j < 4; ++j) {
                int kcol = kt * 64 + tj * 4 + j;
                s[i][j] = (kcol <= qrow) ? s[i][j] * 0.125f : -1e30f;
            }
        }

        float p[4][4], scale_i[4];
        #pragma unroll
        for (int i = 0; i < 4; ++i) {
            float tm = fmaxf(fmaxf(s[i][0], s[i][1]), fmaxf(s[i][2], s[i][3]));
            tm = fmaxf(tm, __shfl_xor(tm, 1));
            tm = fmaxf(tm, __shfl_xor(tm, 2));
            tm = fmaxf(tm, __shfl_xor(tm, 4));
            tm = fmaxf(tm, __shfl_xor(tm, 8));
            float mnew = fmaxf(m_run[i], tm);
            scale_i[i] = __expf(m_run[i] - mnew);
            float ts = 0.f;
            #pragma unroll
            for (int j = 0; j < 4; ++j) { p[i][j] = __expf(s[i][j] - mnew); ts += p[i][j]; }
            ts += __shfl_xor(ts, 1); ts += __shfl_xor(ts, 2);
            ts += __shfl_xor(ts, 4); ts += __shfl_xor(ts, 8);
            l_run[i] = l_run[i] * scale_i[i] + ts;
            m_run[i] = mnew;
        }
        #pragma unroll
        for (int i = 0; i < 4; ++i)
            #pragma unroll
            for (int j = 0; j < 4; ++j) O[i][j] *= scale_i[i];

        const int baseLane = tid & 48;
        #pragma unroll 4
        for (int c4 = 0; c4 < 16; ++c4) {
            int src = baseLane + c4;
            #pragma unroll
            for (int jj = 0; jj < 4; ++jj) {
                float4 vf = *(const float4*)&Vs[c4 * 4 + jj][tj * 4];
                float p0 = __shfl(p[0][jj], src);
                float p1 = __shfl(p[1][jj], src);
                float p2 = __shfl(p[2][jj], src);
                float p3 = __shfl(p[3][jj], src);
                O[0][0] += p0 * vf.x; O[0][1] += p0 * vf.y; O[0][2] += p0 * vf.z; O[0][3] += p0 * vf.w;
                O[1][0] += p1 * vf.x; O[1][1] += p1 * vf.y; O[1][2] += p1 * vf.z; O[1][3] += p1 * vf.w;
                O[2][0] += p2 * vf.x; O[2][1] += p2 * vf.y; O[2][2] += p2 * vf.z; O[2][3] += p2 * vf.w;
                O[3][0] += p3 * vf.x; O[3][1] += p3 * vf.y; O[3][2] += p3 * vf.z; O[3][3] += p3 * vf.w;
            }
        }
    }

    #pragma unroll
    for (int i = 0; i < 4; ++i) {
        float inv = 1.0f / l_run[i];
        float4 o;
        o.x = O[i][0] * inv; o.y = O[i][1] * inv;
        o.z = O[i][2] * inv; o.w = O[i][3] * inv;
        *(float4*)&y[(size_t)(b * T_ + q0 + ti * 4 + i) * C_ + h * HD_ + tj * 4] = o;
    }
}

// ---------------------------------------------------------------- launch

extern "C" void kernel_launch(void* const* d_in, const int* in_sizes, int n_in,
                              void* d_out, int out_size, void* d_ws, size_t ws_size,
                              hipStream_t stream)
{
    (void)in_sizes; (void)n_in; (void)out_size; (void)ws_size;
    const float* x     = (const float*)d_in[0];
    const float* w_in  = (const float*)d_in[1];
    const float* w_out = (const float*)d_in[2];
    float* out  = (float*)d_out;

    float* scal = (float*)d_ws;
    float* qkv  = scal + 64;                                  // 48 MB f32
    float* y    = qkv + (size_t)BT_ * (3 * C_);               // 16 MB f32
    unsigned short* Aq = (unsigned short*)(y + (size_t)BT_ * C_);  // 16 MB fp16 (reused for Yq)
    unsigned short* Wq = Aq + (size_t)BT_ * KTOT;             // 12 MB fp16 (reused for w_out)

    hipMemsetAsync(d_ws, 0, 256, stream);

    reduce_w_kernel<<<dim3(256), 256, 0, stream>>>(w_in,  3 * C_ * C_ / 4, &scal[SLOT_SUMW_IN]);
    reduce_w_kernel<<<dim3(128), 256, 0, stream>>>(w_out, C_ * C_ / 4,     &scal[SLOT_SUMW_OUT]);
    reduce_x_kernel<<<dim3(128, B_), 256, 0, stream>>>(x, scal, SLOT_SUMX, SLOT_SUMSQX, SLOT_GAMMA_X);

    quant_act_kernel<<<dim3(1024), 256, 0, stream>>>(x, Aq, scal, SLOT_SUMX, SLOT_SUMSQX, SLOT_GAMMA_X);
    quant_w_kernel<<<dim3(1024), 256, 0, stream>>>(w_in, Wq, scal, SLOT_SUMW_IN,
                                                   1.0f / (float)(3 * C_ * C_), 3 * C_ * C_ / 4);

    mfma_gemm_kernel<<<dim3(3 * C_ / 128, BT_ / 128), 256, 0, stream>>>(
        Aq, Wq, qkv, scal, 3 * C_, SLOT_SUMW_IN, SLOT_GAMMA_X, 1.0f / (float)(3 * C_ * C_));

    attention_kernel<<<dim3(T_ / 64, NH_, B_), 256, 0, stream>>>(qkv, y);

    reduce_x_kernel<<<dim3(128, B_), 256, 0, stream>>>(y, scal, SLOT_SUMY, SLOT_SUMSQY, SLOT_GAMMA_Y);

    quant_act_kernel<<<dim3(1024), 256, 0, stream>>>(y, Aq, scal, SLOT_SUMY, SLOT_SUMSQY, SLOT_GAMMA_Y);
    quant_w_kernel<<<dim3(512), 256, 0, stream>>>(w_out, Wq, scal, SLOT_SUMW_OUT,
                                                  1.0f / (float)(C_ * C_), C_ * C_ / 4);

    mfma_gemm_kernel<<<dim3(C_ / 128, BT_ / 128), 256, 0, stream>>>(
        Aq, Wq, out, scal, C_, SLOT_SUMW_OUT, SLOT_GAMMA_Y, 1.0f / (float)(C_ * C_));
}

// Round 6
// 354.294 us; speedup vs baseline: 2.8437x; 1.7518x over previous
//
#include <hip/hip_runtime.h>
#include <math.h>

// Problem sizes (fixed by the reference)
#define B_   4
#define T_   1024
#define C_   1024
#define BT_  4096
#define NH_  16
#define HD_  64
#define QB_F 128.0f
#define EPS_F 1e-5f
#define KTOT 2048   // hi|lo concatenated K

// scalar workspace slots (floats at d_ws base)
#define SLOT_SUMW_IN   0
#define SLOT_SUMW_OUT  2
#define SLOT_GAMMA_X   4
#define SLOT_GAMMA_Y   5
#define SLOT_SUMX      8
#define SLOT_SUMSQX    12
#define SLOT_SUMY      16
#define SLOT_SUMSQY    20

typedef __attribute__((ext_vector_type(8))) _Float16 half8;
typedef __attribute__((ext_vector_type(4))) _Float16 half4;
typedef __attribute__((ext_vector_type(4))) float    f32x4;

__device__ __forceinline__ half8 cvt8(float4 a, float4 b) {
    half8 h;
    h[0]=(_Float16)a.x; h[1]=(_Float16)a.y; h[2]=(_Float16)a.z; h[3]=(_Float16)a.w;
    h[4]=(_Float16)b.x; h[5]=(_Float16)b.y; h[6]=(_Float16)b.z; h[7]=(_Float16)b.w;
    return h;
}

__device__ __forceinline__ unsigned short f2h(float f) {
    union { _Float16 h; unsigned short u; } cv; cv.h = (_Float16)f; return cv.u;
}

// ---------------------------------------------------------------- reductions

__global__ void reduce_w_kernel(const float* __restrict__ w, int n4,
                                float* __restrict__ sums)
{
    float s = 0.f, sa = 0.f;
    const int stride = gridDim.x * blockDim.x;
    for (int i = blockIdx.x * blockDim.x + threadIdx.x; i < n4; i += stride) {
        float4 v = ((const float4*)w)[i];
        s  += v.x + v.y + v.z + v.w;
        sa += fabsf(v.x) + fabsf(v.y) + fabsf(v.z) + fabsf(v.w);
    }
    #pragma unroll
    for (int o = 32; o > 0; o >>= 1) {
        s  += __shfl_down(s, o);
        sa += __shfl_down(sa, o);
    }
    __shared__ float sm[8];
    const int lane = threadIdx.x & 63, wid = threadIdx.x >> 6;
    if (lane == 0) { sm[wid] = s; sm[4 + wid] = sa; }
    __syncthreads();
    if (threadIdx.x == 0) {
        atomicAdd(&sums[0], sm[0] + sm[1] + sm[2] + sm[3]);
        atomicAdd(&sums[1], sm[4] + sm[5] + sm[6] + sm[7]);
    }
}

__global__ void reduce_x_kernel(const float* __restrict__ x, float* __restrict__ scal,
                                int sum_base, int sumsq_base, int gamma_slot)
{
    const int b = blockIdx.y;
    const float4* xb = (const float4*)(x + (size_t)b * T_ * C_);
    const int n4 = T_ * C_ / 4;
    float s = 0.f, ss = 0.f, am = 0.f;
    const int stride = gridDim.x * blockDim.x;
    for (int i = blockIdx.x * blockDim.x + threadIdx.x; i < n4; i += stride) {
        float4 v = xb[i];
        s  += v.x + v.y + v.z + v.w;
        ss += v.x*v.x + v.y*v.y + v.z*v.z + v.w*v.w;
        am = fmaxf(am, fmaxf(fmaxf(fabsf(v.x), fabsf(v.y)),
                             fmaxf(fabsf(v.z), fabsf(v.w))));
    }
    #pragma unroll
    for (int o = 32; o > 0; o >>= 1) {
        s  += __shfl_down(s, o);
        ss += __shfl_down(ss, o);
        am  = fmaxf(am, __shfl_down(am, o));
    }
    __shared__ float sm[12];
    const int lane = threadIdx.x & 63, wid = threadIdx.x >> 6;
    if (lane == 0) { sm[wid] = s; sm[4 + wid] = ss; sm[8 + wid] = am; }
    __syncthreads();
    if (threadIdx.x == 0) {
        atomicAdd(&scal[sum_base + b],   sm[0] + sm[1] + sm[2] + sm[3]);
        atomicAdd(&scal[sumsq_base + b], sm[4] + sm[5] + sm[6] + sm[7]);
        float m = fmaxf(fmaxf(sm[8], sm[9]), fmaxf(sm[10], sm[11]));
        atomicMax((unsigned int*)&scal[gamma_slot], __float_as_uint(m));
    }
}

// ---------------------------------------------------------------- quantize passes
__global__ void quant_act_kernel(const float* __restrict__ src, unsigned short* __restrict__ dst,
                                 const float* __restrict__ scal,
                                 int sum_base, int sumsq_base, int gamma_slot)
{
    const int n4 = BT_ * C_ / 4;
    const int stride = gridDim.x * blockDim.x;
    const float gamma = scal[gamma_slot];
    const float invTC = 1.0f / (float)(T_ * C_);
    const float qlo = -QB_F + EPS_F, qhi = QB_F - EPS_F;
    for (int i = blockIdx.x * blockDim.x + threadIdx.x; i < n4; i += stride) {
        const int row = i >> 8;
        const int k   = (i & 255) * 4;
        const int b   = row >> 10;
        const float mu  = scal[sum_base + b] * invTC;
        const float var = scal[sumsq_base + b] * invTC - mu * mu;
        const float am  = (QB_F / gamma) / sqrtf(var + EPS_F);
        float4 v = ((const float4*)src)[i];
        float q[4];
        q[0] = fminf(fmaxf((v.x - mu) * am, qlo), qhi);
        q[1] = fminf(fmaxf((v.y - mu) * am, qlo), qhi);
        q[2] = fminf(fmaxf((v.z - mu) * am, qlo), qhi);
        q[3] = fminf(fmaxf((v.w - mu) * am, qlo), qhi);
        half4 hi, lo;
        #pragma unroll
        for (int j = 0; j < 4; ++j) {
            _Float16 h = (_Float16)q[j];
            hi[j] = h;
            lo[j] = (_Float16)(q[j] - (float)h);
        }
        *(half4*)&dst[(size_t)row * KTOT + k]        = hi;
        *(half4*)&dst[(size_t)row * KTOT + 1024 + k] = lo;
    }
}

__global__ void quant_w_kernel(const float* __restrict__ w, unsigned short* __restrict__ dst,
                               const float* __restrict__ scal, int sumw_slot, float inv_nw,
                               int n4)
{
    const float alpha = scal[sumw_slot] * inv_nw;
    const int stride = gridDim.x * blockDim.x;
    for (int i = blockIdx.x * blockDim.x + threadIdx.x; i < n4; i += stride) {
        const int row = i >> 8;
        const int k   = (i & 255) * 4;
        float4 v = ((const float4*)w)[i];
        half4 s;
        s[0] = (v.x > alpha) ? (_Float16)1.0f : ((v.x < alpha) ? (_Float16)-1.0f : (_Float16)0.0f);
        s[1] = (v.y > alpha) ? (_Float16)1.0f : ((v.y < alpha) ? (_Float16)-1.0f : (_Float16)0.0f);
        s[2] = (v.z > alpha) ? (_Float16)1.0f : ((v.z < alpha) ? (_Float16)-1.0f : (_Float16)0.0f);
        s[3] = (v.w > alpha) ? (_Float16)1.0f : ((v.w < alpha) ? (_Float16)-1.0f : (_Float16)0.0f);
        *(half4*)&dst[(size_t)row * KTOT + k]        = s;
        *(half4*)&dst[(size_t)row * KTOT + 1024 + k] = s;
    }
}

// ---------------------------------------------------------------- MFMA GEMM (validated r5)

__device__ __forceinline__ void gload_lds16(const void* g, void* l)
{
    __builtin_amdgcn_global_load_lds(
        (const __attribute__((address_space(1))) unsigned int*)g,
        (__attribute__((address_space(3))) unsigned int*)l, 16, 0, 0);
}

__global__ __launch_bounds__(256) void mfma_gemm_kernel(
    const unsigned short* __restrict__ A,   // [M][2048]
    const unsigned short* __restrict__ Bm,  // [N][2048]
    float* __restrict__ Out,                // [M][N]
    const float* __restrict__ scal, int N,
    int sumw_slot, int gamma_slot, float inv_nw)
{
    __shared__ __attribute__((aligned(16))) unsigned short As[128 * 32];
    __shared__ __attribute__((aligned(16))) unsigned short Bs[128 * 32];

    const int tid  = threadIdx.x;
    const int row0 = blockIdx.y * 128;
    const int col0 = blockIdx.x * 128;

    const float beta  = scal[sumw_slot + 1] * inv_nw;
    const float gamma = scal[gamma_slot];
    const float out_scale = beta * gamma / QB_F;

    const int wid = tid >> 6, lane = tid & 63;
    const int wr = (wid >> 1) * 64, wc = (wid & 1) * 64;
    const int lrow = lane & 15, lk = (lane >> 4) * 8;

    const int c0r = tid >> 2;
    const int c0k = (tid & 3) * 8;

    f32x4 acc[4][4];
    #pragma unroll
    for (int m = 0; m < 4; ++m)
        #pragma unroll
        for (int n = 0; n < 4; ++n)
            acc[m][n] = (f32x4){0.f, 0.f, 0.f, 0.f};

    for (int kt = 0; kt < KTOT; kt += 32) {
        __syncthreads();
        gload_lds16(&A [(size_t)(row0 +      c0r) * KTOT + kt + c0k], &As[c0r * 32 + c0k]);
        gload_lds16(&A [(size_t)(row0 + 64 + c0r) * KTOT + kt + c0k], &As[(64 + c0r) * 32 + c0k]);
        gload_lds16(&Bm[(size_t)(col0 +      c0r) * KTOT + kt + c0k], &Bs[c0r * 32 + c0k]);
        gload_lds16(&Bm[(size_t)(col0 + 64 + c0r) * KTOT + kt + c0k], &Bs[(64 + c0r) * 32 + c0k]);
        __syncthreads();

        half8 a[4], b[4];
        #pragma unroll
        for (int m = 0; m < 4; ++m)
            a[m] = *(const half8*)&As[(wr + m * 16 + lrow) * 32 + lk];
        #pragma unroll
        for (int n = 0; n < 4; ++n)
            b[n] = *(const half8*)&Bs[(wc + n * 16 + lrow) * 32 + lk];
        #pragma unroll
        for (int m = 0; m < 4; ++m)
            #pragma unroll
            for (int n = 0; n < 4; ++n)
                acc[m][n] = __builtin_amdgcn_mfma_f32_16x16x32_f16(a[m], b[n], acc[m][n], 0, 0, 0);
    }

    const int orow = (lane >> 4) * 4;
    const int ocol = lane & 15;
    #pragma unroll
    for (int m = 0; m < 4; ++m)
        #pragma unroll
        for (int n = 0; n < 4; ++n)
            #pragma unroll
            for (int q = 0; q < 4; ++q)
                Out[(size_t)(row0 + wr + m * 16 + orow + q) * N + col0 + wc + n * 16 + ocol]
                    = acc[m][n][q] * out_scale;
}

// ---------------------------------------------------------------- MFMA flash attention
// Block: 4 waves x 16 q-rows (QBLK=64), k-tiles of 64. Swapped QK^T (S^T=mfma(K,Q))
// so softmax rows are lane-local (q=lane&15); P bounced via per-wave swizzled LDS.
// K LDS: [64][64] f16, 128B rows, XOR swizzle byte^=((row&7)<<4)  [guide G4]
// V LDS: transposed [64 d][68 k] f16 (136B rows, pad kills bank conflicts)
// fp16 inputs / fp32 MFMA accum / fp32 online softmax.
__global__ __launch_bounds__(256) void attn_mfma_kernel(
    const float* __restrict__ qkv, float* __restrict__ y)
{
    __shared__ __attribute__((aligned(16))) unsigned short Kl[64 * 64];
    __shared__ __attribute__((aligned(16))) unsigned short Vt[64 * 68];
    __shared__ __attribute__((aligned(16))) unsigned short Pl[4][16 * 64];

    const int tid = threadIdx.x;
    const int qt = gridDim.x - 1 - blockIdx.x;   // LPT: heavy blocks first
    const int h = blockIdx.y, b = blockIdx.z;
    const int q0 = qt * 64;
    const int wid = tid >> 6, lane = tid & 63;
    const int lq = lane & 15;        // fragment row / q-row owner
    const int lt = lane >> 4;        // 0..3
    const size_t rs = 3 * C_;
    const float* qkvB = qkv + (size_t)b * T_ * rs + h * HD_;

    // Q fragment in registers: rows q0+wid*16+lq, d = lt*8 + 32c + j
    const int qrow = q0 + wid * 16 + lq;
    half8 qf[2];
    #pragma unroll
    for (int c = 0; c < 2; ++c) {
        const float* src = &qkvB[(size_t)qrow * rs + lt * 8 + 32 * c];
        qf[c] = cvt8(*(const float4*)src, *(const float4*)(src + 4));
    }

    f32x4 accO[4];
    #pragma unroll
    for (int n = 0; n < 4; ++n) accO[n] = (f32x4){0.f, 0.f, 0.f, 0.f};
    float m_run = -1e30f, l_run = 0.f;

    unsigned short* Pw = &Pl[wid][0];

    for (int kt = 0; kt <= qt; ++kt) {
        const int k0 = kt * 64;
        __syncthreads();
        // stage K -> Kl (swizzled b128 writes)
        #pragma unroll
        for (int it = 0; it < 2; ++it) {
            int slot = it * 256 + tid;
            int r  = slot >> 3;               // 0..63
            int d8 = (slot & 7) * 8;
            const float* src = &qkvB[C_ + (size_t)(k0 + r) * rs + d8];
            half8 hv = cvt8(*(const float4*)src, *(const float4*)(src + 4));
            *(half8*)((char*)Kl + ((r * 128 + d8 * 2) ^ ((r & 7) << 4))) = hv;
        }
        // stage V -> Vt transposed (scalar writes, padded rows)
        #pragma unroll
        for (int it = 0; it < 4; ++it) {
            int slot = it * 256 + tid;
            int k  = slot >> 4;               // 0..63
            int d0 = (slot & 15) * 4;
            float4 v = *(const float4*)&qkvB[2 * C_ + (size_t)(k0 + k) * rs + d0];
            Vt[(d0 + 0) * 68 + k] = f2h(v.x);
            Vt[(d0 + 1) * 68 + k] = f2h(v.y);
            Vt[(d0 + 2) * 68 + k] = f2h(v.z);
            Vt[(d0 + 3) * 68 + k] = f2h(v.w);
        }
        __syncthreads();

        // QK^T -> S^T (4 m-tiles along k)
        f32x4 accS[4];
        #pragma unroll
        for (int m = 0; m < 4; ++m) accS[m] = (f32x4){0.f, 0.f, 0.f, 0.f};
        #pragma unroll
        for (int m = 0; m < 4; ++m) {
            const int rr = m * 16 + lq;
            const int rswz = (rr & 7) << 4;
            #pragma unroll
            for (int c = 0; c < 2; ++c) {
                half8 kf = *(const half8*)((const char*)Kl + ((rr * 128 + 64 * c + 16 * lt) ^ rswz));
                accS[m] = __builtin_amdgcn_mfma_f32_16x16x32_f16(kf, qf[c], accS[m], 0, 0, 0);
            }
        }

        // online softmax over lane-local row q=lq (16 k-values per lane)
        float p[4][4];
        float mt = -1e30f;
        #pragma unroll
        for (int m = 0; m < 4; ++m)
            #pragma unroll
            for (int qq = 0; qq < 4; ++qq) {
                float s = accS[m][qq] * 0.125f;
                if (kt == qt) {
                    int kg = k0 + 16 * m + 4 * lt + qq;
                    if (kg > qrow) s = -1e30f;
                }
                p[m][qq] = s;
                mt = fmaxf(mt, s);
            }
        mt = fmaxf(mt, __shfl_xor(mt, 16));
        mt = fmaxf(mt, __shfl_xor(mt, 32));
        float mnew = fmaxf(m_run, mt);
        float sc = __expf(m_run - mnew);
        float ps = 0.f;
        #pragma unroll
        for (int m = 0; m < 4; ++m)
            #pragma unroll
            for (int qq = 0; qq < 4; ++qq) {
                float e = __expf(p[m][qq] - mnew);
                p[m][qq] = e;
                ps += e;
            }
        ps += __shfl_xor(ps, 16);
        ps += __shfl_xor(ps, 32);
        l_run = l_run * sc + ps;
        m_run = mnew;

        // rescale accO rows (row index lt*4+qq; sc held at lane lt*4+qq)
        float srow[4];
        #pragma unroll
        for (int qq = 0; qq < 4; ++qq) srow[qq] = __shfl(sc, lt * 4 + qq);
        #pragma unroll
        for (int n = 0; n < 4; ++n) {
            accO[n][0] *= srow[0]; accO[n][1] *= srow[1];
            accO[n][2] *= srow[2]; accO[n][3] *= srow[3];
        }

        // P -> per-wave LDS (swizzled), then read back as A-fragment
        #pragma unroll
        for (int m = 0; m < 4; ++m) {
            half4 ph;
            ph[0] = (_Float16)p[m][0]; ph[1] = (_Float16)p[m][1];
            ph[2] = (_Float16)p[m][2]; ph[3] = (_Float16)p[m][3];
            *(half4*)((char*)Pw + ((lq * 128 + 32 * m + 8 * lt) ^ ((lq & 7) << 4))) = ph;
        }
        asm volatile("s_waitcnt lgkmcnt(0)" ::: "memory");

        // PV: accO[n] += P(16x64) * V^T-frag
        #pragma unroll
        for (int c = 0; c < 2; ++c) {
            half8 pf = *(const half8*)((const char*)Pw + ((lq * 128 + 64 * c + 16 * lt) ^ ((lq & 7) << 4)));
            #pragma unroll
            for (int n = 0; n < 4; ++n) {
                const char* vr = (const char*)&Vt[(16 * n + lq) * 68] + 64 * c + 16 * lt;
                half4 v0 = *(const half4*)vr;
                half4 v1 = *(const half4*)(vr + 8);
                half8 vf;
                vf[0]=v0[0]; vf[1]=v0[1]; vf[2]=v0[2]; vf[3]=v0[3];
                vf[4]=v1[0]; vf[5]=v1[1]; vf[6]=v1[2]; vf[7]=v1[3];
                accO[n] = __builtin_amdgcn_mfma_f32_16x16x32_f16(pf, vf, accO[n], 0, 0, 0);
            }
        }
    }

    // epilogue: O rows = lt*4+qq (within wave tile), cols = 16n+lq
    float linv[4];
    #pragma unroll
    for (int qq = 0; qq < 4; ++qq) linv[qq] = 1.0f / __shfl(l_run, lt * 4 + qq);
    #pragma unroll
    for (int qq = 0; qq < 4; ++qq) {
        const size_t yrow = (size_t)(b * T_ + q0 + wid * 16 + lt * 4 + qq) * C_ + h * HD_;
        #pragma unroll
        for (int n = 0; n < 4; ++n)
            y[yrow + 16 * n + lq] = accO[n][qq] * linv[qq];
    }
}

// ---------------------------------------------------------------- launch

extern "C" void kernel_launch(void* const* d_in, const int* in_sizes, int n_in,
                              void* d_out, int out_size, void* d_ws, size_t ws_size,
                              hipStream_t stream)
{
    (void)in_sizes; (void)n_in; (void)out_size; (void)ws_size;
    const float* x     = (const float*)d_in[0];
    const float* w_in  = (const float*)d_in[1];
    const float* w_out = (const float*)d_in[2];
    float* out  = (float*)d_out;

    float* scal = (float*)d_ws;
    float* qkv  = scal + 64;                                  // 48 MB f32
    float* y    = qkv + (size_t)BT_ * (3 * C_);               // 16 MB f32
    unsigned short* Aq = (unsigned short*)(y + (size_t)BT_ * C_);  // 16 MB fp16 (reused for Yq)
    unsigned short* Wq = Aq + (size_t)BT_ * KTOT;             // 12 MB fp16 (reused for w_out)

    hipMemsetAsync(d_ws, 0, 256, stream);

    reduce_w_kernel<<<dim3(256), 256, 0, stream>>>(w_in,  3 * C_ * C_ / 4, &scal[SLOT_SUMW_IN]);
    reduce_w_kernel<<<dim3(128), 256, 0, stream>>>(w_out, C_ * C_ / 4,     &scal[SLOT_SUMW_OUT]);
    reduce_x_kernel<<<dim3(128, B_), 256, 0, stream>>>(x, scal, SLOT_SUMX, SLOT_SUMSQX, SLOT_GAMMA_X);

    quant_act_kernel<<<dim3(1024), 256, 0, stream>>>(x, Aq, scal, SLOT_SUMX, SLOT_SUMSQX, SLOT_GAMMA_X);
    quant_w_kernel<<<dim3(1024), 256, 0, stream>>>(w_in, Wq, scal, SLOT_SUMW_IN,
                                                   1.0f / (float)(3 * C_ * C_), 3 * C_ * C_ / 4);

    mfma_gemm_kernel<<<dim3(3 * C_ / 128, BT_ / 128), 256, 0, stream>>>(
        Aq, Wq, qkv, scal, 3 * C_, SLOT_SUMW_IN, SLOT_GAMMA_X, 1.0f / (float)(3 * C_ * C_));

    attn_mfma_kernel<<<dim3(T_ / 64, NH_, B_), 256, 0, stream>>>(qkv, y);

    reduce_x_kernel<<<dim3(128, B_), 256, 0, stream>>>(y, scal, SLOT_SUMY, SLOT_SUMSQY, SLOT_GAMMA_Y);

    quant_act_kernel<<<dim3(1024), 256, 0, stream>>>(y, Aq, scal, SLOT_SUMY, SLOT_SUMSQY, SLOT_GAMMA_Y);
    quant_w_kernel<<<dim3(512), 256, 0, stream>>>(w_out, Wq, scal, SLOT_SUMW_OUT,
                                                  1.0f / (float)(C_ * C_), C_ * C_ / 4);

    mfma_gemm_kernel<<<dim3(C_ / 128, BT_ / 128), 256, 0, stream>>>(
        Aq, Wq, out, scal, C_, SLOT_SUMW_OUT, SLOT_GAMMA_Y, 1.0f / (float)(C_ * C_));
}

// Round 7
// 292.218 us; speedup vs baseline: 3.4477x; 1.2124x over previous
//
#include <hip/hip_runtime.h>
#include <math.h>

// Problem sizes (fixed by the reference)
#define B_   4
#define T_   1024
#define C_   1024
#define BT_  4096
#define NH_  16
#define HD_  64
#define QB_F 128.0f
#define EPS_F 1e-5f
#define KTOT 2048   // hi|lo concatenated K

// scalar workspace slots (floats at d_ws base)
#define SLOT_SUMW_IN   0
#define SLOT_SUMW_OUT  2
#define SLOT_GAMMA_X   4
#define SLOT_GAMMA_Y   5
#define SLOT_SUMX      8
#define SLOT_SUMSQX    12
#define SLOT_SUMY      16
#define SLOT_SUMSQY    20

typedef __attribute__((ext_vector_type(8))) _Float16 half8;
typedef __attribute__((ext_vector_type(4))) _Float16 half4;
typedef __attribute__((ext_vector_type(4))) float    f32x4;

__device__ __forceinline__ unsigned short f2h(float f) {
    union { _Float16 h; unsigned short u; } cv; cv.h = (_Float16)f; return cv.u;
}

// ---------------------------------------------------------------- reductions

__global__ void reduce_w_kernel(const float* __restrict__ w, int n4,
                                float* __restrict__ sums)
{
    float s = 0.f, sa = 0.f;
    const int stride = gridDim.x * blockDim.x;
    for (int i = blockIdx.x * blockDim.x + threadIdx.x; i < n4; i += stride) {
        float4 v = ((const float4*)w)[i];
        s  += v.x + v.y + v.z + v.w;
        sa += fabsf(v.x) + fabsf(v.y) + fabsf(v.z) + fabsf(v.w);
    }
    #pragma unroll
    for (int o = 32; o > 0; o >>= 1) {
        s  += __shfl_down(s, o);
        sa += __shfl_down(sa, o);
    }
    __shared__ float sm[8];
    const int lane = threadIdx.x & 63, wid = threadIdx.x >> 6;
    if (lane == 0) { sm[wid] = s; sm[4 + wid] = sa; }
    __syncthreads();
    if (threadIdx.x == 0) {
        atomicAdd(&sums[0], sm[0] + sm[1] + sm[2] + sm[3]);
        atomicAdd(&sums[1], sm[4] + sm[5] + sm[6] + sm[7]);
    }
}

__global__ void reduce_x_kernel(const float* __restrict__ x, float* __restrict__ scal,
                                int sum_base, int sumsq_base, int gamma_slot)
{
    const int b = blockIdx.y;
    const float4* xb = (const float4*)(x + (size_t)b * T_ * C_);
    const int n4 = T_ * C_ / 4;
    float s = 0.f, ss = 0.f, am = 0.f;
    const int stride = gridDim.x * blockDim.x;
    for (int i = blockIdx.x * blockDim.x + threadIdx.x; i < n4; i += stride) {
        float4 v = xb[i];
        s  += v.x + v.y + v.z + v.w;
        ss += v.x*v.x + v.y*v.y + v.z*v.z + v.w*v.w;
        am = fmaxf(am, fmaxf(fmaxf(fabsf(v.x), fabsf(v.y)),
                             fmaxf(fabsf(v.z), fabsf(v.w))));
    }
    #pragma unroll
    for (int o = 32; o > 0; o >>= 1) {
        s  += __shfl_down(s, o);
        ss += __shfl_down(ss, o);
        am  = fmaxf(am, __shfl_down(am, o));
    }
    __shared__ float sm[12];
    const int lane = threadIdx.x & 63, wid = threadIdx.x >> 6;
    if (lane == 0) { sm[wid] = s; sm[4 + wid] = ss; sm[8 + wid] = am; }
    __syncthreads();
    if (threadIdx.x == 0) {
        atomicAdd(&scal[sum_base + b],   sm[0] + sm[1] + sm[2] + sm[3]);
        atomicAdd(&scal[sumsq_base + b], sm[4] + sm[5] + sm[6] + sm[7]);
        float m = fmaxf(fmaxf(sm[8], sm[9]), fmaxf(sm[10], sm[11]));
        atomicMax((unsigned int*)&scal[gamma_slot], __float_as_uint(m));
    }
}

// ---------------------------------------------------------------- quantize passes
__global__ void quant_act_kernel(const float* __restrict__ src, unsigned short* __restrict__ dst,
                                 const float* __restrict__ scal,
                                 int sum_base, int sumsq_base, int gamma_slot)
{
    const int n4 = BT_ * C_ / 4;
    const int stride = gridDim.x * blockDim.x;
    const float gamma = scal[gamma_slot];
    const float invTC = 1.0f / (float)(T_ * C_);
    const float qlo = -QB_F + EPS_F, qhi = QB_F - EPS_F;
    for (int i = blockIdx.x * blockDim.x + threadIdx.x; i < n4; i += stride) {
        const int row = i >> 8;
        const int k   = (i & 255) * 4;
        const int b   = row >> 10;
        const float mu  = scal[sum_base + b] * invTC;
        const float var = scal[sumsq_base + b] * invTC - mu * mu;
        const float am  = (QB_F / gamma) / sqrtf(var + EPS_F);
        float4 v = ((const float4*)src)[i];
        float q[4];
        q[0] = fminf(fmaxf((v.x - mu) * am, qlo), qhi);
        q[1] = fminf(fmaxf((v.y - mu) * am, qlo), qhi);
        q[2] = fminf(fmaxf((v.z - mu) * am, qlo), qhi);
        q[3] = fminf(fmaxf((v.w - mu) * am, qlo), qhi);
        half4 hi, lo;
        #pragma unroll
        for (int j = 0; j < 4; ++j) {
            _Float16 h = (_Float16)q[j];
            hi[j] = h;
            lo[j] = (_Float16)(q[j] - (float)h);
        }
        *(half4*)&dst[(size_t)row * KTOT + k]        = hi;
        *(half4*)&dst[(size_t)row * KTOT + 1024 + k] = lo;
    }
}

__global__ void quant_w_kernel(const float* __restrict__ w, unsigned short* __restrict__ dst,
                               const float* __restrict__ scal, int sumw_slot, float inv_nw,
                               int n4)
{
    const float alpha = scal[sumw_slot] * inv_nw;
    const int stride = gridDim.x * blockDim.x;
    for (int i = blockIdx.x * blockDim.x + threadIdx.x; i < n4; i += stride) {
        const int row = i >> 8;
        const int k   = (i & 255) * 4;
        float4 v = ((const float4*)w)[i];
        half4 s;
        s[0] = (v.x > alpha) ? (_Float16)1.0f : ((v.x < alpha) ? (_Float16)-1.0f : (_Float16)0.0f);
        s[1] = (v.y > alpha) ? (_Float16)1.0f : ((v.y < alpha) ? (_Float16)-1.0f : (_Float16)0.0f);
        s[2] = (v.z > alpha) ? (_Float16)1.0f : ((v.z < alpha) ? (_Float16)-1.0f : (_Float16)0.0f);
        s[3] = (v.w > alpha) ? (_Float16)1.0f : ((v.w < alpha) ? (_Float16)-1.0f : (_Float16)0.0f);
        *(half4*)&dst[(size_t)row * KTOT + k]        = s;
        *(half4*)&dst[(size_t)row * KTOT + 1024 + k] = s;
    }
}

// ---------------------------------------------------------------- MFMA GEMM (structure validated r5/r6)
// If OutH != null: write fp16. Cols < 2C -> OutH[r][c]; cols >= 2C (V region) ->
// VtG[b][h][d][t] pre-transposed for attention. Else write f32 Out.

__device__ __forceinline__ void gload_lds16(const void* g, void* l)
{
    __builtin_amdgcn_global_load_lds(
        (const __attribute__((address_space(1))) unsigned int*)g,
        (__attribute__((address_space(3))) unsigned int*)l, 16, 0, 0);
}

__global__ __launch_bounds__(256) void mfma_gemm_kernel(
    const unsigned short* __restrict__ A,   // [M][2048]
    const unsigned short* __restrict__ Bm,  // [N][2048]
    float* __restrict__ Out,                // [M][N] f32 (or null)
    unsigned short* __restrict__ OutH,      // [M][N] f16 (or null)
    unsigned short* __restrict__ VtG,       // [B][NH][HD][T] f16 (or null)
    const float* __restrict__ scal, int N,
    int sumw_slot, int gamma_slot, float inv_nw)
{
    __shared__ __attribute__((aligned(16))) unsigned short As[128 * 32];
    __shared__ __attribute__((aligned(16))) unsigned short Bs[128 * 32];

    const int tid  = threadIdx.x;
    const int row0 = blockIdx.y * 128;
    const int col0 = blockIdx.x * 128;

    const float beta  = scal[sumw_slot + 1] * inv_nw;
    const float gamma = scal[gamma_slot];
    const float out_scale = beta * gamma / QB_F;

    const int wid = tid >> 6, lane = tid & 63;
    const int wr = (wid >> 1) * 64, wc = (wid & 1) * 64;
    const int lrow = lane & 15, lk = (lane >> 4) * 8;

    const int c0r = tid >> 2;
    const int c0k = (tid & 3) * 8;

    f32x4 acc[4][4];
    #pragma unroll
    for (int m = 0; m < 4; ++m)
        #pragma unroll
        for (int n = 0; n < 4; ++n)
            acc[m][n] = (f32x4){0.f, 0.f, 0.f, 0.f};

    for (int kt = 0; kt < KTOT; kt += 32) {
        __syncthreads();
        gload_lds16(&A [(size_t)(row0 +      c0r) * KTOT + kt + c0k], &As[c0r * 32 + c0k]);
        gload_lds16(&A [(size_t)(row0 + 64 + c0r) * KTOT + kt + c0k], &As[(64 + c0r) * 32 + c0k]);
        gload_lds16(&Bm[(size_t)(col0 +      c0r) * KTOT + kt + c0k], &Bs[c0r * 32 + c0k]);
        gload_lds16(&Bm[(size_t)(col0 + 64 + c0r) * KTOT + kt + c0k], &Bs[(64 + c0r) * 32 + c0k]);
        __syncthreads();

        half8 a[4], b[4];
        #pragma unroll
        for (int m = 0; m < 4; ++m)
            a[m] = *(const half8*)&As[(wr + m * 16 + lrow) * 32 + lk];
        #pragma unroll
        for (int n = 0; n < 4; ++n)
            b[n] = *(const half8*)&Bs[(wc + n * 16 + lrow) * 32 + lk];
        #pragma unroll
        for (int m = 0; m < 4; ++m)
            #pragma unroll
            for (int n = 0; n < 4; ++n)
                acc[m][n] = __builtin_amdgcn_mfma_f32_16x16x32_f16(a[m], b[n], acc[m][n], 0, 0, 0);
    }

    // D layout: col = lane&15, row = (lane>>4)*4 + q  [m89-verified]
    const int orow = (lane >> 4) * 4;
    const int ocol = lane & 15;
    #pragma unroll
    for (int m = 0; m < 4; ++m) {
        const int gr0 = row0 + wr + m * 16 + orow;
        #pragma unroll
        for (int n = 0; n < 4; ++n) {
            const int c = col0 + wc + n * 16 + ocol;
            if (OutH) {
                if (c < 2 * C_) {
                    #pragma unroll
                    for (int q = 0; q < 4; ++q)
                        OutH[(size_t)(gr0 + q) * N + c] = f2h(acc[m][n][q] * out_scale);
                } else {
                    const int hh = (c - 2 * C_) >> 6, dd = (c - 2 * C_) & 63;
                    const int bb = gr0 >> 10,         tt = gr0 & 1023;
                    half4 hv;
                    hv[0] = (_Float16)(acc[m][n][0] * out_scale);
                    hv[1] = (_Float16)(acc[m][n][1] * out_scale);
                    hv[2] = (_Float16)(acc[m][n][2] * out_scale);
                    hv[3] = (_Float16)(acc[m][n][3] * out_scale);
                    *(half4*)&VtG[(((size_t)bb * NH_ + hh) * HD_ + dd) * T_ + tt] = hv;
                }
            } else {
                #pragma unroll
                for (int q = 0; q < 4; ++q)
                    Out[(size_t)(gr0 + q) * N + c] = acc[m][n][q] * out_scale;
            }
        }
    }
}

// ---------------------------------------------------------------- MFMA flash attention
// 8 waves x 16 q-rows (QBLK=128), k-tiles of 64. fp16 Q/K from qkvH, fp16 V^T from vtG.
// K/V staged via global_load_lds w16: linear LDS dest (byte = tid*16), PRE-SWIZZLED
// global source granule (^(row&7)), read side uses the validated XOR  byte^((row&7)<<4).
// Swapped QK^T (S^T = mfma(K,Q)) -> lane-local softmax rows; P bounced via per-wave LDS.
__global__ __launch_bounds__(512) void attn_mfma_kernel(
    const unsigned short* __restrict__ qkvH,  // [BT][3C] f16 (Q,K cols valid)
    const unsigned short* __restrict__ vtG,   // [B][NH][HD][T] f16
    float* __restrict__ y)
{
    __shared__ __attribute__((aligned(16))) unsigned short Kl[64 * 64];
    __shared__ __attribute__((aligned(16))) unsigned short Vl[64 * 64];
    __shared__ __attribute__((aligned(16))) unsigned short Pl[8][16 * 64];

    const int tid = threadIdx.x;
    const int qt = gridDim.x - 1 - blockIdx.x;   // LPT: heavy blocks first
    const int h = blockIdx.y, b = blockIdx.z;
    const int q0 = qt * 128;
    const int wid = tid >> 6, lane = tid & 63;
    const int lq = lane & 15, lt = lane >> 4;
    const size_t rsH = 3 * C_;
    const unsigned short* qkvB = qkvH + (size_t)b * T_ * rsH + h * HD_;
    const unsigned short* vtB  = vtG + ((size_t)b * NH_ + h) * HD_ * T_;

    // Q fragment in registers (rows q0+wid*16+lq, kk = lt*8 within 32-chunk c)
    const int qrow = q0 + wid * 16 + lq;
    half8 qf[2];
    qf[0] = *(const half8*)&qkvB[(size_t)qrow * rsH + lt * 8];
    qf[1] = *(const half8*)&qkvB[(size_t)qrow * rsH + lt * 8 + 32];

    f32x4 accO[4];
    #pragma unroll
    for (int n = 0; n < 4; ++n) accO[n] = (f32x4){0.f, 0.f, 0.f, 0.f};
    float m_run = -1e30f, l_run = 0.f;

    unsigned short* Pw = &Pl[wid][0];

    // staging: LDS byte = tid*16 (linear); row = tid>>3; source granule pre-swizzled
    const int strow = tid >> 3;                          // 0..63
    const int sgr   = (((tid & 7) ^ (strow & 7)) << 3);  // swizzled half-offset in row

    const int nkt = 2 * qt + 2;
    for (int kt = 0; kt < nkt; ++kt) {
        const int k0 = kt * 64;
        __syncthreads();
        gload_lds16(&qkvB[(size_t)(k0 + strow) * rsH + C_ + sgr], &Kl[tid * 8]);
        gload_lds16(&vtB [(size_t)strow * T_ + k0 + sgr],         &Vl[tid * 8]);
        __syncthreads();

        // QK^T -> S^T
        f32x4 accS[4];
        #pragma unroll
        for (int m = 0; m < 4; ++m) accS[m] = (f32x4){0.f, 0.f, 0.f, 0.f};
        #pragma unroll
        for (int m = 0; m < 4; ++m) {
            const int rr = m * 16 + lq;
            const int rswz = (rr & 7) << 4;
            #pragma unroll
            for (int c = 0; c < 2; ++c) {
                half8 kf = *(const half8*)((const char*)Kl + ((rr * 128 + 64 * c + 16 * lt) ^ rswz));
                accS[m] = __builtin_amdgcn_mfma_f32_16x16x32_f16(kf, qf[c], accS[m], 0, 0, 0);
            }
        }

        // online softmax over lane-local row q (16 k-values per lane)
        float p[4][4];
        float mt = -1e30f;
        #pragma unroll
        for (int m = 0; m < 4; ++m)
            #pragma unroll
            for (int qq = 0; qq < 4; ++qq) {
                float s = accS[m][qq] * 0.125f;
                int kg = k0 + 16 * m + 4 * lt + qq;
                if (kg > qrow) s = -1e30f;
                p[m][qq] = s;
                mt = fmaxf(mt, s);
            }
        mt = fmaxf(mt, __shfl_xor(mt, 16));
        mt = fmaxf(mt, __shfl_xor(mt, 32));
        float mnew = fmaxf(m_run, mt);
        float sc = __expf(m_run - mnew);
        float ps = 0.f;
        #pragma unroll
        for (int m = 0; m < 4; ++m)
            #pragma unroll
            for (int qq = 0; qq < 4; ++qq) {
                float e = __expf(p[m][qq] - mnew);
                p[m][qq] = e;
                ps += e;
            }
        ps += __shfl_xor(ps, 16);
        ps += __shfl_xor(ps, 32);
        l_run = l_run * sc + ps;
        m_run = mnew;

        // rescale accO (O row = lt*4+qq; its scale lives at lane lt*4+qq)
        float srw[4];
        #pragma unroll
        for (int qq = 0; qq < 4; ++qq) srw[qq] = __shfl(sc, lt * 4 + qq);
        #pragma unroll
        for (int n = 0; n < 4; ++n) {
            accO[n][0] *= srw[0]; accO[n][1] *= srw[1];
            accO[n][2] *= srw[2]; accO[n][3] *= srw[3];
        }

        // P -> per-wave swizzled LDS, read back as A-fragment
        #pragma unroll
        for (int m = 0; m < 4; ++m) {
            half4 ph;
            ph[0] = (_Float16)p[m][0]; ph[1] = (_Float16)p[m][1];
            ph[2] = (_Float16)p[m][2]; ph[3] = (_Float16)p[m][3];
            *(half4*)((char*)Pw + ((lq * 128 + 32 * m + 8 * lt) ^ ((lq & 7) << 4))) = ph;
        }
        asm volatile("s_waitcnt lgkmcnt(0)" ::: "memory");
        __builtin_amdgcn_sched_barrier(0);

        // PV: accO[n] += P(16x64) * V^T
        #pragma unroll
        for (int c = 0; c < 2; ++c) {
            half8 pf = *(const half8*)((const char*)Pw + ((lq * 128 + 64 * c + 16 * lt) ^ ((lq & 7) << 4)));
            #pragma unroll
            for (int n = 0; n < 4; ++n) {
                const int dr = 16 * n + lq;
                half8 vf = *(const half8*)((const char*)Vl + ((dr * 128 + 64 * c + 16 * lt) ^ ((dr & 7) << 4)));
                accO[n] = __builtin_amdgcn_mfma_f32_16x16x32_f16(pf, vf, accO[n], 0, 0, 0);
            }
        }
    }

    // epilogue: O rows = lt*4+qq (within wave tile), cols d = 16n+lq
    float linv[4];
    #pragma unroll
    for (int qq = 0; qq < 4; ++qq) linv[qq] = 1.0f / __shfl(l_run, lt * 4 + qq);
    #pragma unroll
    for (int qq = 0; qq < 4; ++qq) {
        const size_t yrow = (size_t)(b * T_ + q0 + wid * 16 + lt * 4 + qq) * C_ + h * HD_;
        #pragma unroll
        for (int n = 0; n < 4; ++n)
            y[yrow + 16 * n + lq] = accO[n][qq] * linv[qq];
    }
}

// ---------------------------------------------------------------- launch

extern "C" void kernel_launch(void* const* d_in, const int* in_sizes, int n_in,
                              void* d_out, int out_size, void* d_ws, size_t ws_size,
                              hipStream_t stream)
{
    (void)in_sizes; (void)n_in; (void)out_size; (void)ws_size;
    const float* x     = (const float*)d_in[0];
    const float* w_in  = (const float*)d_in[1];
    const float* w_out = (const float*)d_in[2];
    float* out  = (float*)d_out;

    float* scal = (float*)d_ws;
    unsigned short* qkvH = (unsigned short*)(scal + 64);          // 24 MB f16 [BT][3C]
    unsigned short* vtG  = qkvH + (size_t)BT_ * 3 * C_;           // 8 MB f16 [B][NH][HD][T]
    float* y = (float*)(vtG + (size_t)B_ * NH_ * HD_ * T_);       // 16 MB f32
    unsigned short* Aq = (unsigned short*)(y + (size_t)BT_ * C_); // 16 MB f16
    unsigned short* Wq = Aq + (size_t)BT_ * KTOT;                 // 12 MB f16

    hipMemsetAsync(d_ws, 0, 256, stream);

    reduce_w_kernel<<<dim3(256), 256, 0, stream>>>(w_in,  3 * C_ * C_ / 4, &scal[SLOT_SUMW_IN]);
    reduce_w_kernel<<<dim3(128), 256, 0, stream>>>(w_out, C_ * C_ / 4,     &scal[SLOT_SUMW_OUT]);
    reduce_x_kernel<<<dim3(128, B_), 256, 0, stream>>>(x, scal, SLOT_SUMX, SLOT_SUMSQX, SLOT_GAMMA_X);

    quant_act_kernel<<<dim3(1024), 256, 0, stream>>>(x, Aq, scal, SLOT_SUMX, SLOT_SUMSQX, SLOT_GAMMA_X);
    quant_w_kernel<<<dim3(1024), 256, 0, stream>>>(w_in, Wq, scal, SLOT_SUMW_IN,
                                                   1.0f / (float)(3 * C_ * C_), 3 * C_ * C_ / 4);

    // GEMM1: fp16 outputs (Q,K -> qkvH; V -> vtG transposed)
    mfma_gemm_kernel<<<dim3(3 * C_ / 128, BT_ / 128), 256, 0, stream>>>(
        Aq, Wq, nullptr, qkvH, vtG, scal, 3 * C_, SLOT_SUMW_IN, SLOT_GAMMA_X,
        1.0f / (float)(3 * C_ * C_));

    attn_mfma_kernel<<<dim3(T_ / 128, NH_, B_), 512, 0, stream>>>(qkvH, vtG, y);

    reduce_x_kernel<<<dim3(128, B_), 256, 0, stream>>>(y, scal, SLOT_SUMY, SLOT_SUMSQY, SLOT_GAMMA_Y);

    quant_act_kernel<<<dim3(1024), 256, 0, stream>>>(y, Aq, scal, SLOT_SUMY, SLOT_SUMSQY, SLOT_GAMMA_Y);
    quant_w_kernel<<<dim3(512), 256, 0, stream>>>(w_out, Wq, scal, SLOT_SUMW_OUT,
                                                  1.0f / (float)(C_ * C_), C_ * C_ / 4);

    // GEMM2: f32 output
    mfma_gemm_kernel<<<dim3(C_ / 128, BT_ / 128), 256, 0, stream>>>(
        Aq, Wq, out, nullptr, nullptr, scal, C_, SLOT_SUMW_OUT, SLOT_GAMMA_Y,
        1.0f / (float)(C_ * C_));
}

// Round 8
// 232.966 us; speedup vs baseline: 4.3246x; 1.2543x over previous
//
#include <hip/hip_runtime.h>
#include <math.h>

// Problem sizes (fixed by the reference)
#define B_   4
#define T_   1024
#define C_   1024
#define BT_  4096
#define NH_  16
#define HD_  64
#define QB_F 128.0f
#define EPS_F 1e-5f
#define KACT 1024   // pure-fp16 activations (lo-residual dropped r8)

// scalar workspace slots (floats at d_ws base)
#define SLOT_SUMW_IN   0
#define SLOT_SUMW_OUT  2
#define SLOT_GAMMA_X   4
#define SLOT_GAMMA_Y   5
#define SLOT_SUMX      8
#define SLOT_SUMSQX    12
#define SLOT_SUMY      16
#define SLOT_SUMSQY    20

typedef __attribute__((ext_vector_type(8))) _Float16 half8;
typedef __attribute__((ext_vector_type(4))) _Float16 half4;
typedef __attribute__((ext_vector_type(4))) float    f32x4;

__device__ __forceinline__ unsigned short f2h(float f) {
    union { _Float16 h; unsigned short u; } cv; cv.h = (_Float16)f; return cv.u;
}

// ---------------------------------------------------------------- reductions

__global__ void reduce_w_kernel(const float* __restrict__ w, int n4,
                                float* __restrict__ sums)
{
    float s = 0.f, sa = 0.f;
    const int stride = gridDim.x * blockDim.x;
    for (int i = blockIdx.x * blockDim.x + threadIdx.x; i < n4; i += stride) {
        float4 v = ((const float4*)w)[i];
        s  += v.x + v.y + v.z + v.w;
        sa += fabsf(v.x) + fabsf(v.y) + fabsf(v.z) + fabsf(v.w);
    }
    #pragma unroll
    for (int o = 32; o > 0; o >>= 1) {
        s  += __shfl_down(s, o);
        sa += __shfl_down(sa, o);
    }
    __shared__ float sm[8];
    const int lane = threadIdx.x & 63, wid = threadIdx.x >> 6;
    if (lane == 0) { sm[wid] = s; sm[4 + wid] = sa; }
    __syncthreads();
    if (threadIdx.x == 0) {
        atomicAdd(&sums[0], sm[0] + sm[1] + sm[2] + sm[3]);
        atomicAdd(&sums[1], sm[4] + sm[5] + sm[6] + sm[7]);
    }
}

__global__ void reduce_x_kernel(const float* __restrict__ x, float* __restrict__ scal,
                                int sum_base, int sumsq_base, int gamma_slot)
{
    const int b = blockIdx.y;
    const float4* xb = (const float4*)(x + (size_t)b * T_ * C_);
    const int n4 = T_ * C_ / 4;
    float s = 0.f, ss = 0.f, am = 0.f;
    const int stride = gridDim.x * blockDim.x;
    for (int i = blockIdx.x * blockDim.x + threadIdx.x; i < n4; i += stride) {
        float4 v = xb[i];
        s  += v.x + v.y + v.z + v.w;
        ss += v.x*v.x + v.y*v.y + v.z*v.z + v.w*v.w;
        am = fmaxf(am, fmaxf(fmaxf(fabsf(v.x), fabsf(v.y)),
                             fmaxf(fabsf(v.z), fabsf(v.w))));
    }
    #pragma unroll
    for (int o = 32; o > 0; o >>= 1) {
        s  += __shfl_down(s, o);
        ss += __shfl_down(ss, o);
        am  = fmaxf(am, __shfl_down(am, o));
    }
    __shared__ float sm[12];
    const int lane = threadIdx.x & 63, wid = threadIdx.x >> 6;
    if (lane == 0) { sm[wid] = s; sm[4 + wid] = ss; sm[8 + wid] = am; }
    __syncthreads();
    if (threadIdx.x == 0) {
        atomicAdd(&scal[sum_base + b],   sm[0] + sm[1] + sm[2] + sm[3]);
        atomicAdd(&scal[sumsq_base + b], sm[4] + sm[5] + sm[6] + sm[7]);
        float m = fmaxf(fmaxf(sm[8], sm[9]), fmaxf(sm[10], sm[11]));
        atomicMax((unsigned int*)&scal[gamma_slot], __float_as_uint(m));
    }
}

// ---------------------------------------------------------------- quantize passes
__global__ void quant_act_kernel(const float* __restrict__ src, unsigned short* __restrict__ dst,
                                 const float* __restrict__ scal,
                                 int sum_base, int sumsq_base, int gamma_slot)
{
    const int n4 = BT_ * C_ / 4;
    const int stride = gridDim.x * blockDim.x;
    const float gamma = scal[gamma_slot];
    const float invTC = 1.0f / (float)(T_ * C_);
    const float qlo = -QB_F + EPS_F, qhi = QB_F - EPS_F;
    for (int i = blockIdx.x * blockDim.x + threadIdx.x; i < n4; i += stride) {
        const int row = i >> 8;
        const int k   = (i & 255) * 4;
        const int b   = row >> 10;
        const float mu  = scal[sum_base + b] * invTC;
        const float var = scal[sumsq_base + b] * invTC - mu * mu;
        const float am  = (QB_F / gamma) / sqrtf(var + EPS_F);
        float4 v = ((const float4*)src)[i];
        half4 hi;
        hi[0] = (_Float16)fminf(fmaxf((v.x - mu) * am, qlo), qhi);
        hi[1] = (_Float16)fminf(fmaxf((v.y - mu) * am, qlo), qhi);
        hi[2] = (_Float16)fminf(fmaxf((v.z - mu) * am, qlo), qhi);
        hi[3] = (_Float16)fminf(fmaxf((v.w - mu) * am, qlo), qhi);
        *(half4*)&dst[(size_t)row * KACT + k] = hi;
    }
}

__global__ void quant_w_kernel(const float* __restrict__ w, unsigned short* __restrict__ dst,
                               const float* __restrict__ scal, int sumw_slot, float inv_nw,
                               int n4)
{
    const float alpha = scal[sumw_slot] * inv_nw;
    const int stride = gridDim.x * blockDim.x;
    for (int i = blockIdx.x * blockDim.x + threadIdx.x; i < n4; i += stride) {
        const int row = i >> 8;
        const int k   = (i & 255) * 4;
        float4 v = ((const float4*)w)[i];
        half4 s;
        s[0] = (v.x > alpha) ? (_Float16)1.0f : ((v.x < alpha) ? (_Float16)-1.0f : (_Float16)0.0f);
        s[1] = (v.y > alpha) ? (_Float16)1.0f : ((v.y < alpha) ? (_Float16)-1.0f : (_Float16)0.0f);
        s[2] = (v.z > alpha) ? (_Float16)1.0f : ((v.z < alpha) ? (_Float16)-1.0f : (_Float16)0.0f);
        s[3] = (v.w > alpha) ? (_Float16)1.0f : ((v.w < alpha) ? (_Float16)-1.0f : (_Float16)0.0f);
        *(half4*)&dst[(size_t)row * KACT + k] = s;
    }
}

// ---------------------------------------------------------------- MFMA GEMM (structure validated r5-r7)
// If OutH != null: cols < 2C -> OutH f16; cols >= 2C (V) -> VtG[b][h][d][t] f16. Else f32 Out.

__device__ __forceinline__ void gload_lds16(const void* g, void* l)
{
    __builtin_amdgcn_global_load_lds(
        (const __attribute__((address_space(1))) unsigned int*)g,
        (__attribute__((address_space(3))) unsigned int*)l, 16, 0, 0);
}

__global__ __launch_bounds__(256) void mfma_gemm_kernel(
    const unsigned short* __restrict__ A,   // [M][1024] f16
    const unsigned short* __restrict__ Bm,  // [N][1024] f16
    float* __restrict__ Out,                // [M][N] f32 (or null)
    unsigned short* __restrict__ OutH,      // [M][N] f16 (or null)
    unsigned short* __restrict__ VtG,       // [B][NH][HD][T] f16 (or null)
    const float* __restrict__ scal, int N,
    int sumw_slot, int gamma_slot, float inv_nw)
{
    __shared__ __attribute__((aligned(16))) unsigned short As[128 * 32];
    __shared__ __attribute__((aligned(16))) unsigned short Bs[128 * 32];

    const int tid  = threadIdx.x;
    const int row0 = blockIdx.y * 128;
    const int col0 = blockIdx.x * 128;

    const float beta  = scal[sumw_slot + 1] * inv_nw;
    const float gamma = scal[gamma_slot];
    const float out_scale = beta * gamma / QB_F;

    const int wid = tid >> 6, lane = tid & 63;
    const int wr = (wid >> 1) * 64, wc = (wid & 1) * 64;
    const int lrow = lane & 15, lk = (lane >> 4) * 8;

    const int c0r = tid >> 2;
    const int c0k = (tid & 3) * 8;

    f32x4 acc[4][4];
    #pragma unroll
    for (int m = 0; m < 4; ++m)
        #pragma unroll
        for (int n = 0; n < 4; ++n)
            acc[m][n] = (f32x4){0.f, 0.f, 0.f, 0.f};

    for (int kt = 0; kt < KACT; kt += 32) {
        __syncthreads();
        gload_lds16(&A [(size_t)(row0 +      c0r) * KACT + kt + c0k], &As[c0r * 32 + c0k]);
        gload_lds16(&A [(size_t)(row0 + 64 + c0r) * KACT + kt + c0k], &As[(64 + c0r) * 32 + c0k]);
        gload_lds16(&Bm[(size_t)(col0 +      c0r) * KACT + kt + c0k], &Bs[c0r * 32 + c0k]);
        gload_lds16(&Bm[(size_t)(col0 + 64 + c0r) * KACT + kt + c0k], &Bs[(64 + c0r) * 32 + c0k]);
        __syncthreads();

        half8 a[4], b[4];
        #pragma unroll
        for (int m = 0; m < 4; ++m)
            a[m] = *(const half8*)&As[(wr + m * 16 + lrow) * 32 + lk];
        #pragma unroll
        for (int n = 0; n < 4; ++n)
            b[n] = *(const half8*)&Bs[(wc + n * 16 + lrow) * 32 + lk];
        #pragma unroll
        for (int m = 0; m < 4; ++m)
            #pragma unroll
            for (int n = 0; n < 4; ++n)
                acc[m][n] = __builtin_amdgcn_mfma_f32_16x16x32_f16(a[m], b[n], acc[m][n], 0, 0, 0);
    }

    // D layout: col = lane&15, row = (lane>>4)*4 + q  [m89-verified]
    const int orow = (lane >> 4) * 4;
    const int ocol = lane & 15;
    #pragma unroll
    for (int m = 0; m < 4; ++m) {
        const int gr0 = row0 + wr + m * 16 + orow;
        #pragma unroll
        for (int n = 0; n < 4; ++n) {
            const int c = col0 + wc + n * 16 + ocol;
            if (OutH) {
                if (c < 2 * C_) {
                    #pragma unroll
                    for (int q = 0; q < 4; ++q)
                        OutH[(size_t)(gr0 + q) * N + c] = f2h(acc[m][n][q] * out_scale);
                } else {
                    const int hh = (c - 2 * C_) >> 6, dd = (c - 2 * C_) & 63;
                    const int bb = gr0 >> 10,         tt = gr0 & 1023;
                    half4 hv;
                    hv[0] = (_Float16)(acc[m][n][0] * out_scale);
                    hv[1] = (_Float16)(acc[m][n][1] * out_scale);
                    hv[2] = (_Float16)(acc[m][n][2] * out_scale);
                    hv[3] = (_Float16)(acc[m][n][3] * out_scale);
                    *(half4*)&VtG[(((size_t)bb * NH_ + hh) * HD_ + dd) * T_ + tt] = hv;
                }
            } else {
                #pragma unroll
                for (int q = 0; q < 4; ++q)
                    Out[(size_t)(gr0 + q) * N + c] = acc[m][n][q] * out_scale;
            }
        }
    }
}

// ---------------------------------------------------------------- MFMA flash attention (r7-validated)
// + r8: y-stats (per-batch sum/sumsq/max|y|) folded into the epilogue.
__global__ __launch_bounds__(512) void attn_mfma_kernel(
    const unsigned short* __restrict__ qkvH,  // [BT][3C] f16 (Q,K cols valid)
    const unsigned short* __restrict__ vtG,   // [B][NH][HD][T] f16
    float* __restrict__ y, float* __restrict__ scal)
{
    __shared__ __attribute__((aligned(16))) unsigned short Kl[64 * 64];
    __shared__ __attribute__((aligned(16))) unsigned short Vl[64 * 64];
    __shared__ __attribute__((aligned(16))) unsigned short Pl[8][16 * 64];

    const int tid = threadIdx.x;
    const int qt = gridDim.x - 1 - blockIdx.x;   // LPT: heavy blocks first
    const int h = blockIdx.y, b = blockIdx.z;
    const int q0 = qt * 128;
    const int wid = tid >> 6, lane = tid & 63;
    const int lq = lane & 15, lt = lane >> 4;
    const size_t rsH = 3 * C_;
    const unsigned short* qkvB = qkvH + (size_t)b * T_ * rsH + h * HD_;
    const unsigned short* vtB  = vtG + ((size_t)b * NH_ + h) * HD_ * T_;

    const int qrow = q0 + wid * 16 + lq;
    half8 qf[2];
    qf[0] = *(const half8*)&qkvB[(size_t)qrow * rsH + lt * 8];
    qf[1] = *(const half8*)&qkvB[(size_t)qrow * rsH + lt * 8 + 32];

    f32x4 accO[4];
    #pragma unroll
    for (int n = 0; n < 4; ++n) accO[n] = (f32x4){0.f, 0.f, 0.f, 0.f};
    float m_run = -1e30f, l_run = 0.f;

    unsigned short* Pw = &Pl[wid][0];

    const int strow = tid >> 3;
    const int sgr   = (((tid & 7) ^ (strow & 7)) << 3);

    const int nkt = 2 * qt + 2;
    for (int kt = 0; kt < nkt; ++kt) {
        const int k0 = kt * 64;
        __syncthreads();
        gload_lds16(&qkvB[(size_t)(k0 + strow) * rsH + C_ + sgr], &Kl[tid * 8]);
        gload_lds16(&vtB [(size_t)strow * T_ + k0 + sgr],         &Vl[tid * 8]);
        __syncthreads();

        f32x4 accS[4];
        #pragma unroll
        for (int m = 0; m < 4; ++m) accS[m] = (f32x4){0.f, 0.f, 0.f, 0.f};
        #pragma unroll
        for (int m = 0; m < 4; ++m) {
            const int rr = m * 16 + lq;
            const int rswz = (rr & 7) << 4;
            #pragma unroll
            for (int c = 0; c < 2; ++c) {
                half8 kf = *(const half8*)((const char*)Kl + ((rr * 128 + 64 * c + 16 * lt) ^ rswz));
                accS[m] = __builtin_amdgcn_mfma_f32_16x16x32_f16(kf, qf[c], accS[m], 0, 0, 0);
            }
        }

        float p[4][4];
        float mt = -1e30f;
        #pragma unroll
        for (int m = 0; m < 4; ++m)
            #pragma unroll
            for (int qq = 0; qq < 4; ++qq) {
                float s = accS[m][qq] * 0.125f;
                int kg = k0 + 16 * m + 4 * lt + qq;
                if (kg > qrow) s = -1e30f;
                p[m][qq] = s;
                mt = fmaxf(mt, s);
            }
        mt = fmaxf(mt, __shfl_xor(mt, 16));
        mt = fmaxf(mt, __shfl_xor(mt, 32));
        float mnew = fmaxf(m_run, mt);
        float sc = __expf(m_run - mnew);
        float ps = 0.f;
        #pragma unroll
        for (int m = 0; m < 4; ++m)
            #pragma unroll
            for (int qq = 0; qq < 4; ++qq) {
                float e = __expf(p[m][qq] - mnew);
                p[m][qq] = e;
                ps += e;
            }
        ps += __shfl_xor(ps, 16);
        ps += __shfl_xor(ps, 32);
        l_run = l_run * sc + ps;
        m_run = mnew;

        float srw[4];
        #pragma unroll
        for (int qq = 0; qq < 4; ++qq) srw[qq] = __shfl(sc, lt * 4 + qq);
        #pragma unroll
        for (int n = 0; n < 4; ++n) {
            accO[n][0] *= srw[0]; accO[n][1] *= srw[1];
            accO[n][2] *= srw[2]; accO[n][3] *= srw[3];
        }

        #pragma unroll
        for (int m = 0; m < 4; ++m) {
            half4 ph;
            ph[0] = (_Float16)p[m][0]; ph[1] = (_Float16)p[m][1];
            ph[2] = (_Float16)p[m][2]; ph[3] = (_Float16)p[m][3];
            *(half4*)((char*)Pw + ((lq * 128 + 32 * m + 8 * lt) ^ ((lq & 7) << 4))) = ph;
        }
        asm volatile("s_waitcnt lgkmcnt(0)" ::: "memory");
        __builtin_amdgcn_sched_barrier(0);

        #pragma unroll
        for (int c = 0; c < 2; ++c) {
            half8 pf = *(const half8*)((const char*)Pw + ((lq * 128 + 64 * c + 16 * lt) ^ ((lq & 7) << 4)));
            #pragma unroll
            for (int n = 0; n < 4; ++n) {
                const int dr = 16 * n + lq;
                half8 vf = *(const half8*)((const char*)Vl + ((dr * 128 + 64 * c + 16 * lt) ^ ((dr & 7) << 4)));
                accO[n] = __builtin_amdgcn_mfma_f32_16x16x32_f16(pf, vf, accO[n], 0, 0, 0);
            }
        }
    }

    // epilogue: write y + accumulate per-batch stats
    float linv[4];
    #pragma unroll
    for (int qq = 0; qq < 4; ++qq) linv[qq] = 1.0f / __shfl(l_run, lt * 4 + qq);
    float s_loc = 0.f, ss_loc = 0.f, am_loc = 0.f;
    #pragma unroll
    for (int qq = 0; qq < 4; ++qq) {
        const size_t yrow = (size_t)(b * T_ + q0 + wid * 16 + lt * 4 + qq) * C_ + h * HD_;
        #pragma unroll
        for (int n = 0; n < 4; ++n) {
            float v = accO[n][qq] * linv[qq];
            y[yrow + 16 * n + lq] = v;
            s_loc += v; ss_loc += v * v; am_loc = fmaxf(am_loc, fabsf(v));
        }
    }
    #pragma unroll
    for (int o = 32; o > 0; o >>= 1) {
        s_loc  += __shfl_down(s_loc, o);
        ss_loc += __shfl_down(ss_loc, o);
        am_loc  = fmaxf(am_loc, __shfl_down(am_loc, o));
    }
    __syncthreads();                       // Pl no longer needed by PV
    float* red = (float*)&Pl[0][0];
    if (lane == 0) { red[wid] = s_loc; red[8 + wid] = ss_loc; red[16 + wid] = am_loc; }
    __syncthreads();
    if (tid == 0) {
        float s = 0.f, ss = 0.f, am = 0.f;
        #pragma unroll
        for (int i = 0; i < 8; ++i) {
            s += red[i]; ss += red[8 + i]; am = fmaxf(am, red[16 + i]);
        }
        atomicAdd(&scal[SLOT_SUMY + b], s);
        atomicAdd(&scal[SLOT_SUMSQY + b], ss);
        atomicMax((unsigned int*)&scal[SLOT_GAMMA_Y], __float_as_uint(am));
    }
}

// ---------------------------------------------------------------- launch

extern "C" void kernel_launch(void* const* d_in, const int* in_sizes, int n_in,
                              void* d_out, int out_size, void* d_ws, size_t ws_size,
                              hipStream_t stream)
{
    (void)in_sizes; (void)n_in; (void)out_size; (void)ws_size;
    const float* x     = (const float*)d_in[0];
    const float* w_in  = (const float*)d_in[1];
    const float* w_out = (const float*)d_in[2];
    float* out  = (float*)d_out;

    float* scal = (float*)d_ws;
    unsigned short* qkvH = (unsigned short*)(scal + 64);          // 24 MB f16 [BT][3C]
    unsigned short* vtG  = qkvH + (size_t)BT_ * 3 * C_;           // 8 MB f16 [B][NH][HD][T]
    float* y = (float*)(vtG + (size_t)B_ * NH_ * HD_ * T_);       // 16 MB f32
    unsigned short* Aq = (unsigned short*)(y + (size_t)BT_ * C_); // 8 MB f16
    unsigned short* Wq = Aq + (size_t)BT_ * KACT;                 // 6 MB f16

    hipMemsetAsync(d_ws, 0, 256, stream);

    reduce_w_kernel<<<dim3(256), 256, 0, stream>>>(w_in,  3 * C_ * C_ / 4, &scal[SLOT_SUMW_IN]);
    reduce_w_kernel<<<dim3(128), 256, 0, stream>>>(w_out, C_ * C_ / 4,     &scal[SLOT_SUMW_OUT]);
    reduce_x_kernel<<<dim3(128, B_), 256, 0, stream>>>(x, scal, SLOT_SUMX, SLOT_SUMSQX, SLOT_GAMMA_X);

    quant_act_kernel<<<dim3(1024), 256, 0, stream>>>(x, Aq, scal, SLOT_SUMX, SLOT_SUMSQX, SLOT_GAMMA_X);
    quant_w_kernel<<<dim3(1024), 256, 0, stream>>>(w_in, Wq, scal, SLOT_SUMW_IN,
                                                   1.0f / (float)(3 * C_ * C_), 3 * C_ * C_ / 4);

    // GEMM1: fp16 outputs (Q,K -> qkvH; V -> vtG transposed)
    mfma_gemm_kernel<<<dim3(3 * C_ / 128, BT_ / 128), 256, 0, stream>>>(
        Aq, Wq, nullptr, qkvH, vtG, scal, 3 * C_, SLOT_SUMW_IN, SLOT_GAMMA_X,
        1.0f / (float)(3 * C_ * C_));

    attn_mfma_kernel<<<dim3(T_ / 128, NH_, B_), 512, 0, stream>>>(qkvH, vtG, y, scal);

    quant_act_kernel<<<dim3(1024), 256, 0, stream>>>(y, Aq, scal, SLOT_SUMY, SLOT_SUMSQY, SLOT_GAMMA_Y);
    quant_w_kernel<<<dim3(512), 256, 0, stream>>>(w_out, Wq, scal, SLOT_SUMW_OUT,
                                                  1.0f / (float)(C_ * C_), C_ * C_ / 4);

    // GEMM2: f32 output
    mfma_gemm_kernel<<<dim3(C_ / 128, BT_ / 128), 256, 0, stream>>>(
        Aq, Wq, out, nullptr, nullptr, scal, C_, SLOT_SUMW_OUT, SLOT_GAMMA_Y,
        1.0f / (float)(C_ * C_));
}

// Round 13
// 217.383 us; speedup vs baseline: 4.6346x; 1.0717x over previous
//
#include <hip/hip_runtime.h>
#include <math.h>

// Problem sizes (fixed by the reference)
#define B_   4
#define T_   1024
#define C_   1024
#define BT_  4096
#define NH_  16
#define HD_  64
#define QB_F 128.0f
#define EPS_F 1e-5f
#define KACT 1024   // pure-fp16 activations (validated r8)

// scalar workspace slots (floats at d_ws base)
#define SLOT_SUMW_IN   0
#define SLOT_SUMW_OUT  2
#define SLOT_GAMMA_X   4
#define SLOT_GAMMA_Y   5
#define SLOT_SUMX      8
#define SLOT_SUMSQX    12
#define SLOT_SUMY      16
#define SLOT_SUMSQY    20

typedef __attribute__((ext_vector_type(8))) _Float16 half8;
typedef __attribute__((ext_vector_type(4))) _Float16 half4;
typedef __attribute__((ext_vector_type(4))) float    f32x4;

__device__ __forceinline__ unsigned short f2h(float f) {
    union { _Float16 h; unsigned short u; } cv; cv.h = (_Float16)f; return cv.u;
}

// ---------------------------------------------------------------- fused stats
// grid.x = 896: [0,256) w_in | [256,384) w_out | [384,896) x per-batch (128 blocks/batch)
__global__ void stats_kernel(const float* __restrict__ x,
                             const float* __restrict__ w_in,
                             const float* __restrict__ w_out,
                             float* __restrict__ scal)
{
    __shared__ float sm[12];
    const int tid = threadIdx.x;
    const int lane = tid & 63, wid = tid >> 6;
    const int gb = blockIdx.x;

    if (gb < 384) {
        // weight sum / sumabs
        const float* w; int n4, bi, nb; float* sums;
        if (gb < 256) { w = w_in;  n4 = 3 * C_ * C_ / 4; bi = gb;      nb = 256; sums = &scal[SLOT_SUMW_IN]; }
        else          { w = w_out; n4 = C_ * C_ / 4;     bi = gb - 256; nb = 128; sums = &scal[SLOT_SUMW_OUT]; }
        float s = 0.f, sa = 0.f;
        const int stride = nb * 256;
        for (int i = bi * 256 + tid; i < n4; i += stride) {
            float4 v = ((const float4*)w)[i];
            s  += v.x + v.y + v.z + v.w;
            sa += fabsf(v.x) + fabsf(v.y) + fabsf(v.z) + fabsf(v.w);
        }
        #pragma unroll
        for (int o = 32; o > 0; o >>= 1) {
            s  += __shfl_down(s, o);
            sa += __shfl_down(sa, o);
        }
        if (lane == 0) { sm[wid] = s; sm[4 + wid] = sa; }
        __syncthreads();
        if (tid == 0) {
            atomicAdd(&sums[0], sm[0] + sm[1] + sm[2] + sm[3]);
            atomicAdd(&sums[1], sm[4] + sm[5] + sm[6] + sm[7]);
        }
    } else {
        // x per-batch sum/sumsq + global max
        const int i0 = gb - 384;
        const int b = i0 >> 7, bi = i0 & 127;
        const float4* xb = (const float4*)(x + (size_t)b * T_ * C_);
        const int n4 = T_ * C_ / 4;
        float s = 0.f, ss = 0.f, am = 0.f;
        const int stride = 128 * 256;
        for (int i = bi * 256 + tid; i < n4; i += stride) {
            float4 v = xb[i];
            s  += v.x + v.y + v.z + v.w;
            ss += v.x*v.x + v.y*v.y + v.z*v.z + v.w*v.w;
            am = fmaxf(am, fmaxf(fmaxf(fabsf(v.x), fabsf(v.y)),
                                 fmaxf(fabsf(v.z), fabsf(v.w))));
        }
        #pragma unroll
        for (int o = 32; o > 0; o >>= 1) {
            s  += __shfl_down(s, o);
            ss += __shfl_down(ss, o);
            am  = fmaxf(am, __shfl_down(am, o));
        }
        if (lane == 0) { sm[wid] = s; sm[4 + wid] = ss; sm[8 + wid] = am; }
        __syncthreads();
        if (tid == 0) {
            atomicAdd(&scal[SLOT_SUMX + b],   sm[0] + sm[1] + sm[2] + sm[3]);
            atomicAdd(&scal[SLOT_SUMSQX + b], sm[4] + sm[5] + sm[6] + sm[7]);
            float m = fmaxf(fmaxf(sm[8], sm[9]), fmaxf(sm[10], sm[11]));
            atomicMax((unsigned int*)&scal[SLOT_GAMMA_X], __float_as_uint(m));
        }
    }
}

// ---------------------------------------------------------------- fused prep (quant x + sign w_in + sign w_out)
// grid.x = 2048: [0,1024) quant_act(x) | [1024,1792) quant_w(w_in) | [1792,2048) quant_w(w_out)
__global__ void prep_kernel(const float* __restrict__ x,
                            const float* __restrict__ w_in,
                            const float* __restrict__ w_out,
                            unsigned short* __restrict__ Aq,
                            unsigned short* __restrict__ Wq,
                            unsigned short* __restrict__ WqO,
                            const float* __restrict__ scal)
{
    const int tid = threadIdx.x;
    const int gb = blockIdx.x;

    if (gb < 1024) {
        const int n4 = BT_ * C_ / 4;
        const int stride = 1024 * 256;
        const float gamma = scal[SLOT_GAMMA_X];
        const float invTC = 1.0f / (float)(T_ * C_);
        const float qlo = -QB_F + EPS_F, qhi = QB_F - EPS_F;
        for (int i = gb * 256 + tid; i < n4; i += stride) {
            const int row = i >> 8;
            const int k   = (i & 255) * 4;
            const int b   = row >> 10;
            const float mu  = scal[SLOT_SUMX + b] * invTC;
            const float var = scal[SLOT_SUMSQX + b] * invTC - mu * mu;
            const float am  = (QB_F / gamma) / sqrtf(var + EPS_F);
            float4 v = ((const float4*)x)[i];
            half4 hi;
            hi[0] = (_Float16)fminf(fmaxf((v.x - mu) * am, qlo), qhi);
            hi[1] = (_Float16)fminf(fmaxf((v.y - mu) * am, qlo), qhi);
            hi[2] = (_Float16)fminf(fmaxf((v.z - mu) * am, qlo), qhi);
            hi[3] = (_Float16)fminf(fmaxf((v.w - mu) * am, qlo), qhi);
            *(half4*)&Aq[(size_t)row * KACT + k] = hi;
        }
    } else {
        const float* w; unsigned short* dst; int n4, bi, nb; float alpha;
        if (gb < 1792) {
            w = w_in;  dst = Wq;  n4 = 3 * C_ * C_ / 4; bi = gb - 1024; nb = 768;
            alpha = scal[SLOT_SUMW_IN] / (float)(3 * C_ * C_);
        } else {
            w = w_out; dst = WqO; n4 = C_ * C_ / 4;     bi = gb - 1792; nb = 256;
            alpha = scal[SLOT_SUMW_OUT] / (float)(C_ * C_);
        }
        const int stride = nb * 256;
        for (int i = bi * 256 + tid; i < n4; i += stride) {
            const int row = i >> 8;
            const int k   = (i & 255) * 4;
            float4 v = ((const float4*)w)[i];
            half4 s;
            s[0] = (v.x > alpha) ? (_Float16)1.0f : ((v.x < alpha) ? (_Float16)-1.0f : (_Float16)0.0f);
            s[1] = (v.y > alpha) ? (_Float16)1.0f : ((v.y < alpha) ? (_Float16)-1.0f : (_Float16)0.0f);
            s[2] = (v.z > alpha) ? (_Float16)1.0f : ((v.z < alpha) ? (_Float16)-1.0f : (_Float16)0.0f);
            s[3] = (v.w > alpha) ? (_Float16)1.0f : ((v.w < alpha) ? (_Float16)-1.0f : (_Float16)0.0f);
            *(half4*)&dst[(size_t)row * KACT + k] = s;
        }
    }
}

// ---------------------------------------------------------------- quant y (separate; needs y-stats from attn)
__global__ void quant_act_kernel(const float* __restrict__ src, unsigned short* __restrict__ dst,
                                 const float* __restrict__ scal,
                                 int sum_base, int sumsq_base, int gamma_slot)
{
    const int n4 = BT_ * C_ / 4;
    const int stride = gridDim.x * blockDim.x;
    const float gamma = scal[gamma_slot];
    const float invTC = 1.0f / (float)(T_ * C_);
    const float qlo = -QB_F + EPS_F, qhi = QB_F - EPS_F;
    for (int i = blockIdx.x * blockDim.x + threadIdx.x; i < n4; i += stride) {
        const int row = i >> 8;
        const int k   = (i & 255) * 4;
        const int b   = row >> 10;
        const float mu  = scal[sum_base + b] * invTC;
        const float var = scal[sumsq_base + b] * invTC - mu * mu;
        const float am  = (QB_F / gamma) / sqrtf(var + EPS_F);
        float4 v = ((const float4*)src)[i];
        half4 hi;
        hi[0] = (_Float16)fminf(fmaxf((v.x - mu) * am, qlo), qhi);
        hi[1] = (_Float16)fminf(fmaxf((v.y - mu) * am, qlo), qhi);
        hi[2] = (_Float16)fminf(fmaxf((v.z - mu) * am, qlo), qhi);
        hi[3] = (_Float16)fminf(fmaxf((v.w - mu) * am, qlo), qhi);
        *(half4*)&dst[(size_t)row * KACT + k] = hi;
    }
}

// ---------------------------------------------------------------- MFMA GEMM (structure validated r5-r8)

__device__ __forceinline__ void gload_lds16(const void* g, void* l)
{
    __builtin_amdgcn_global_load_lds(
        (const __attribute__((address_space(1))) unsigned int*)g,
        (__attribute__((address_space(3))) unsigned int*)l, 16, 0, 0);
}

__global__ __launch_bounds__(256) void mfma_gemm_kernel(
    const unsigned short* __restrict__ A,   // [M][1024] f16
    const unsigned short* __restrict__ Bm,  // [N][1024] f16
    float* __restrict__ Out,                // [M][N] f32 (or null)
    unsigned short* __restrict__ OutH,      // [M][N] f16 (or null)
    unsigned short* __restrict__ VtG,       // [B][NH][HD][T] f16 (or null)
    const float* __restrict__ scal, int N,
    int sumw_slot, int gamma_slot, float inv_nw)
{
    __shared__ __attribute__((aligned(16))) unsigned short As[128 * 32];
    __shared__ __attribute__((aligned(16))) unsigned short Bs[128 * 32];

    const int tid  = threadIdx.x;
    const int row0 = blockIdx.y * 128;
    const int col0 = blockIdx.x * 128;

    const float beta  = scal[sumw_slot + 1] * inv_nw;
    const float gamma = scal[gamma_slot];
    const float out_scale = beta * gamma / QB_F;

    const int wid = tid >> 6, lane = tid & 63;
    const int wr = (wid >> 1) * 64, wc = (wid & 1) * 64;
    const int lrow = lane & 15, lk = (lane >> 4) * 8;

    const int c0r = tid >> 2;
    const int c0k = (tid & 3) * 8;

    f32x4 acc[4][4];
    #pragma unroll
    for (int m = 0; m < 4; ++m)
        #pragma unroll
        for (int n = 0; n < 4; ++n)
            acc[m][n] = (f32x4){0.f, 0.f, 0.f, 0.f};

    for (int kt = 0; kt < KACT; kt += 32) {
        __syncthreads();
        gload_lds16(&A [(size_t)(row0 +      c0r) * KACT + kt + c0k], &As[c0r * 32 + c0k]);
        gload_lds16(&A [(size_t)(row0 + 64 + c0r) * KACT + kt + c0k], &As[(64 + c0r) * 32 + c0k]);
        gload_lds16(&Bm[(size_t)(col0 +      c0r) * KACT + kt + c0k], &Bs[c0r * 32 + c0k]);
        gload_lds16(&Bm[(size_t)(col0 + 64 + c0r) * KACT + kt + c0k], &Bs[(64 + c0r) * 32 + c0k]);
        __syncthreads();

        half8 a[4], b[4];
        #pragma unroll
        for (int m = 0; m < 4; ++m)
            a[m] = *(const half8*)&As[(wr + m * 16 + lrow) * 32 + lk];
        #pragma unroll
        for (int n = 0; n < 4; ++n)
            b[n] = *(const half8*)&Bs[(wc + n * 16 + lrow) * 32 + lk];
        #pragma unroll
        for (int m = 0; m < 4; ++m)
            #pragma unroll
            for (int n = 0; n < 4; ++n)
                acc[m][n] = __builtin_amdgcn_mfma_f32_16x16x32_f16(a[m], b[n], acc[m][n], 0, 0, 0);
    }

    // D layout: col = lane&15, row = (lane>>4)*4 + q  [m89-verified]
    const int orow = (lane >> 4) * 4;
    const int ocol = lane & 15;
    #pragma unroll
    for (int m = 0; m < 4; ++m) {
        const int gr0 = row0 + wr + m * 16 + orow;
        #pragma unroll
        for (int n = 0; n < 4; ++n) {
            const int c = col0 + wc + n * 16 + ocol;
            if (OutH) {
                if (c < 2 * C_) {
                    #pragma unroll
                    for (int q = 0; q < 4; ++q)
                        OutH[(size_t)(gr0 + q) * N + c] = f2h(acc[m][n][q] * out_scale);
                } else {
                    const int hh = (c - 2 * C_) >> 6, dd = (c - 2 * C_) & 63;
                    const int bb = gr0 >> 10,         tt = gr0 & 1023;
                    half4 hv;
                    hv[0] = (_Float16)(acc[m][n][0] * out_scale);
                    hv[1] = (_Float16)(acc[m][n][1] * out_scale);
                    hv[2] = (_Float16)(acc[m][n][2] * out_scale);
                    hv[3] = (_Float16)(acc[m][n][3] * out_scale);
                    *(half4*)&VtG[(((size_t)bb * NH_ + hh) * HD_ + dd) * T_ + tt] = hv;
                }
            } else {
                #pragma unroll
                for (int q = 0; q < 4; ++q)
                    Out[(size_t)(gr0 + q) * N + c] = acc[m][n][q] * out_scale;
            }
        }
    }
}

// ---------------------------------------------------------------- MFMA flash attention
// r9: double-buffered K/V staging (2-phase T3-minimum): issue next-tile
// global_load_lds BEFORE computing current tile; one __syncthreads per tile
// (its implicit vmcnt(0)+lgkmcnt(0) drains the prefetch before buffer swap).
__global__ __launch_bounds__(512) void attn_mfma_kernel(
    const unsigned short* __restrict__ qkvH,  // [BT][3C] f16 (Q,K cols valid)
    const unsigned short* __restrict__ vtG,   // [B][NH][HD][T] f16
    float* __restrict__ y, float* __restrict__ scal)
{
    __shared__ __attribute__((aligned(16))) unsigned short Kl[2][64 * 64];
    __shared__ __attribute__((aligned(16))) unsigned short Vl[2][64 * 64];
    __shared__ __attribute__((aligned(16))) unsigned short Pl[8][16 * 64];

    const int tid = threadIdx.x;
    const int qt = gridDim.x - 1 - blockIdx.x;   // LPT: heavy blocks first
    const int h = blockIdx.y, b = blockIdx.z;
    const int q0 = qt * 128;
    const int wid = tid >> 6, lane = tid & 63;
    const int lq = lane & 15, lt = lane >> 4;
    const size_t rsH = 3 * C_;
    const unsigned short* qkvB = qkvH + (size_t)b * T_ * rsH + h * HD_;
    const unsigned short* vtB  = vtG + ((size_t)b * NH_ + h) * HD_ * T_;

    const int qrow = q0 + wid * 16 + lq;
    half8 qf[2];
    qf[0] = *(const half8*)&qkvB[(size_t)qrow * rsH + lt * 8];
    qf[1] = *(const half8*)&qkvB[(size_t)qrow * rsH + lt * 8 + 32];

    f32x4 accO[4];
    #pragma unroll
    for (int n = 0; n < 4; ++n) accO[n] = (f32x4){0.f, 0.f, 0.f, 0.f};
    float m_run = -1e30f, l_run = 0.f;

    unsigned short* Pw = &Pl[wid][0];

    const int strow = tid >> 3;
    const int sgr   = (((tid & 7) ^ (strow & 7)) << 3);

    const int nkt = 2 * qt + 2;
    // prologue: stage tile 0 into buf 0
    gload_lds16(&qkvB[(size_t)strow * rsH + C_ + sgr], &Kl[0][tid * 8]);
    gload_lds16(&vtB [(size_t)strow * T_ + sgr],       &Vl[0][tid * 8]);
    __syncthreads();

    for (int kt = 0; kt < nkt; ++kt) {
        const int k0 = kt * 64;
        const int cur = kt & 1;
        // prefetch next tile into the other buffer (overlaps with compute below)
        if (kt + 1 < nkt) {
            const int kn = k0 + 64;
            gload_lds16(&qkvB[(size_t)(kn + strow) * rsH + C_ + sgr], &Kl[cur ^ 1][tid * 8]);
            gload_lds16(&vtB [(size_t)strow * T_ + kn + sgr],         &Vl[cur ^ 1][tid * 8]);
        }

        f32x4 accS[4];
        #pragma unroll
        for (int m = 0; m < 4; ++m) accS[m] = (f32x4){0.f, 0.f, 0.f, 0.f};
        #pragma unroll
        for (int m = 0; m < 4; ++m) {
            const int rr = m * 16 + lq;
            const int rswz = (rr & 7) << 4;
            #pragma unroll
            for (int c = 0; c < 2; ++c) {
                half8 kf = *(const half8*)((const char*)&Kl[cur][0] + ((rr * 128 + 64 * c + 16 * lt) ^ rswz));
                accS[m] = __builtin_amdgcn_mfma_f32_16x16x32_f16(kf, qf[c], accS[m], 0, 0, 0);
            }
        }

        float p[4][4];
        float mt = -1e30f;
        #pragma unroll
        for (int m = 0; m < 4; ++m)
            #pragma unroll
            for (int qq = 0; qq < 4; ++qq) {
                float s = accS[m][qq] * 0.125f;
                int kg = k0 + 16 * m + 4 * lt + qq;
                if (kg > qrow) s = -1e30f;
                p[m][qq] = s;
                mt = fmaxf(mt, s);
            }
        mt = fmaxf(mt, __shfl_xor(mt, 16));
        mt = fmaxf(mt, __shfl_xor(mt, 32));
        float mnew = fmaxf(m_run, mt);
        float sc = __expf(m_run - mnew);
        float ps = 0.f;
        #pragma unroll
        for (int m = 0; m < 4; ++m)
            #pragma unroll
            for (int qq = 0; qq < 4; ++qq) {
                float e = __expf(p[m][qq] - mnew);
                p[m][qq] = e;
                ps += e;
            }
        ps += __shfl_xor(ps, 16);
        ps += __shfl_xor(ps, 32);
        l_run = l_run * sc + ps;
        m_run = mnew;

        float srw[4];
        #pragma unroll
        for (int qq = 0; qq < 4; ++qq) srw[qq] = __shfl(sc, lt * 4 + qq);
        #pragma unroll
        for (int n = 0; n < 4; ++n) {
            accO[n][0] *= srw[0]; accO[n][1] *= srw[1];
            accO[n][2] *= srw[2]; accO[n][3] *= srw[3];
        }

        #pragma unroll
        for (int m = 0; m < 4; ++m) {
            half4 ph;
            ph[0] = (_Float16)p[m][0]; ph[1] = (_Float16)p[m][1];
            ph[2] = (_Float16)p[m][2]; ph[3] = (_Float16)p[m][3];
            *(half4*)((char*)Pw + ((lq * 128 + 32 * m + 8 * lt) ^ ((lq & 7) << 4))) = ph;
        }
        asm volatile("s_waitcnt lgkmcnt(0)" ::: "memory");   // DS only — prefetch (vmcnt) stays in flight
        __builtin_amdgcn_sched_barrier(0);

        #pragma unroll
        for (int c = 0; c < 2; ++c) {
            half8 pf = *(const half8*)((const char*)Pw + ((lq * 128 + 64 * c + 16 * lt) ^ ((lq & 7) << 4)));
            #pragma unroll
            for (int n = 0; n < 4; ++n) {
                const int dr = 16 * n + lq;
                half8 vf = *(const half8*)((const char*)&Vl[cur][0] + ((dr * 128 + 64 * c + 16 * lt) ^ ((dr & 7) << 4)));
                accO[n] = __builtin_amdgcn_mfma_f32_16x16x32_f16(pf, vf, accO[n], 0, 0, 0);
            }
        }
        __syncthreads();   // drains vmcnt(0): next buffer ready; protects cur for overwrite
    }

    // epilogue: write y + accumulate per-batch stats (r8-validated)
    float linv[4];
    #pragma unroll
    for (int qq = 0; qq < 4; ++qq) linv[qq] = 1.0f / __shfl(l_run, lt * 4 + qq);
    float s_loc = 0.f, ss_loc = 0.f, am_loc = 0.f;
    #pragma unroll
    for (int qq = 0; qq < 4; ++qq) {
        const size_t yrow = (size_t)(b * T_ + q0 + wid * 16 + lt * 4 + qq) * C_ + h * HD_;
        #pragma unroll
        for (int n = 0; n < 4; ++n) {
            float v = accO[n][qq] * linv[qq];
            y[yrow + 16 * n + lq] = v;
            s_loc += v; ss_loc += v * v; am_loc = fmaxf(am_loc, fabsf(v));
        }
    }
    #pragma unroll
    for (int o = 32; o > 0; o >>= 1) {
        s_loc  += __shfl_down(s_loc, o);
        ss_loc += __shfl_down(ss_loc, o);
        am_loc  = fmaxf(am_loc, __shfl_down(am_loc, o));
    }
    __syncthreads();
    float* red = (float*)&Pl[0][0];
    if (lane == 0) { red[wid] = s_loc; red[8 + wid] = ss_loc; red[16 + wid] = am_loc; }
    __syncthreads();
    if (tid == 0) {
        float s = 0.f, ss = 0.f, am = 0.f;
        #pragma unroll
        for (int i = 0; i < 8; ++i) {
            s += red[i]; ss += red[8 + i]; am = fmaxf(am, red[16 + i]);
        }
        atomicAdd(&scal[SLOT_SUMY + b], s);
        atomicAdd(&scal[SLOT_SUMSQY + b], ss);
        atomicMax((unsigned int*)&scal[SLOT_GAMMA_Y], __float_as_uint(am));
    }
}

// ---------------------------------------------------------------- launch

extern "C" void kernel_launch(void* const* d_in, const int* in_sizes, int n_in,
                              void* d_out, int out_size, void* d_ws, size_t ws_size,
                              hipStream_t stream)
{
    (void)in_sizes; (void)n_in; (void)out_size; (void)ws_size;
    const float* x     = (const float*)d_in[0];
    const float* w_in  = (const float*)d_in[1];
    const float* w_out = (const float*)d_in[2];
    float* out  = (float*)d_out;

    float* scal = (float*)d_ws;
    unsigned short* qkvH = (unsigned short*)(scal + 64);          // 24 MB f16 [BT][3C]
    unsigned short* vtG  = qkvH + (size_t)BT_ * 3 * C_;           // 8 MB f16 [B][NH][HD][T]
    float* y = (float*)(vtG + (size_t)B_ * NH_ * HD_ * T_);       // 16 MB f32
    unsigned short* Aq = (unsigned short*)(y + (size_t)BT_ * C_); // 8 MB f16 (x-quant, then y-quant)
    unsigned short* Wq = Aq + (size_t)BT_ * KACT;                 // 6 MB f16 (w_in sign)
    unsigned short* WqO = Wq + (size_t)3 * C_ * KACT;             // 2 MB f16 (w_out sign)

    hipMemsetAsync(d_ws, 0, 256, stream);

    stats_kernel<<<dim3(896), 256, 0, stream>>>(x, w_in, w_out, scal);
    prep_kernel<<<dim3(2048), 256, 0, stream>>>(x, w_in, w_out, Aq, Wq, WqO, scal);

    // GEMM1: fp16 outputs (Q,K -> qkvH; V -> vtG transposed)
    mfma_gemm_kernel<<<dim3(3 * C_ / 128, BT_ / 128), 256, 0, stream>>>(
        Aq, Wq, nullptr, qkvH, vtG, scal, 3 * C_, SLOT_SUMW_IN, SLOT_GAMMA_X,
        1.0f / (float)(3 * C_ * C_));

    attn_mfma_kernel<<<dim3(T_ / 128, NH_, B_), 512, 0, stream>>>(qkvH, vtG, y, scal);

    quant_act_kernel<<<dim3(1024), 256, 0, stream>>>(y, Aq, scal, SLOT_SUMY, SLOT_SUMSQY, SLOT_GAMMA_Y);

    // GEMM2: f32 output
    mfma_gemm_kernel<<<dim3(C_ / 128, BT_ / 128), 256, 0, stream>>>(
        Aq, WqO, out, nullptr, nullptr, scal, C_, SLOT_SUMW_OUT, SLOT_GAMMA_Y,
        1.0f / (float)(C_ * C_));
}